// Round 1
// baseline (707.237 us; speedup 1.0000x reference)
//
#include <hip/hip_runtime.h>
#include <hip/hip_bf16.h>

typedef __bf16 bf16x8 __attribute__((ext_vector_type(8)));
typedef float f32x4 __attribute__((ext_vector_type(4)));

#define HW 4096
#define DIMC 192
#define NHEADS 4
#define DH 48
#define HIDC 510

// ---------------- W transpose: wt[c][o] = w[o][c] ----------------
__global__ void transpose_w_kernel(const float* __restrict__ w, float* __restrict__ wt, int O, int C) {
  int idx = blockIdx.x * 256 + threadIdx.x;
  if (idx >= O * C) return;
  int o = idx / C, c = idx - o * C;
  wt[(size_t)c * O + o] = w[idx];
}

// ---------------- LayerNorm2d: per (b,c) over HW ----------------
__global__ __launch_bounds__(256) void ln_kernel(const float* __restrict__ x, const float* __restrict__ w,
                                                 const float* __restrict__ b, float* __restrict__ out) {
  int bc = blockIdx.x;            // b*DIMC + c
  int c = bc % DIMC;
  const float* row = x + (size_t)bc * HW;
  float* orow = out + (size_t)bc * HW;
  float s = 0.f, s2 = 0.f;
  for (int i = threadIdx.x; i < HW; i += 256) { float v = row[i]; s += v; s2 = fmaf(v, v, s2); }
  __shared__ float red[8];
  for (int off = 32; off; off >>= 1) { s += __shfl_down(s, off, 64); s2 += __shfl_down(s2, off, 64); }
  int wid = threadIdx.x >> 6;
  if ((threadIdx.x & 63) == 0) { red[wid] = s; red[4 + wid] = s2; }
  __syncthreads();
  s = red[0] + red[1] + red[2] + red[3];
  s2 = red[4] + red[5] + red[6] + red[7];
  float mean = s * (1.f / HW);
  float var = s2 * (1.f / HW) - mean * mean;
  float rstd = rsqrtf(var + 1e-6f);
  float sc = rstd * w[c];
  float sh = b[c] - mean * sc;
  for (int i = threadIdx.x; i < HW; i += 256) orow[i] = fmaf(row[i], sc, sh);
}

// ---------------- conv1x1: out[b,o,n] = sum_c Wt[c][o] * X[b,c,n] (+bias, +res) ----------------
// Wt is [C][O]; weight reads are wave-uniform -> scalar loads.
__global__ __launch_bounds__(256) void conv1x1_kernel(const float* __restrict__ X, const float* __restrict__ Wt,
                                                      const float* __restrict__ bias, const float* __restrict__ res,
                                                      float* __restrict__ out, int O, int C) {
  int b = blockIdx.z;
  int n = blockIdx.x * 256 + threadIdx.x;
  int o0 = blockIdx.y * 16;
  if (o0 + 16 > O) o0 = O - 16;   // tail blocks recompute (dup writes of identical values; only used when res==null)
  const float* Xb = X + (size_t)b * C * HW + n;
  float acc[16];
#pragma unroll
  for (int i = 0; i < 16; ++i) acc[i] = 0.f;
#pragma unroll 4
  for (int c = 0; c < C; ++c) {
    float xv = Xb[(size_t)c * HW];
    const float* wr = Wt + (size_t)c * O + o0;
#pragma unroll
    for (int oo = 0; oo < 16; ++oo) acc[oo] = fmaf(wr[oo], xv, acc[oo]);
  }
  size_t base = (size_t)b * O * HW + (size_t)o0 * HW + n;
#pragma unroll
  for (int oo = 0; oo < 16; ++oo) {
    float v = acc[oo] + bias[o0 + oo];
    if (res) v += res[base + (size_t)oo * HW];
    out[base + (size_t)oo * HW] = v;
  }
}

// ---------------- depthwise 3x3, SAME, one (b,ch) plane per block ----------------
__global__ __launch_bounds__(256) void dwconv_kernel(const float* __restrict__ in, const float* __restrict__ w,
                                                     const float* __restrict__ bias, float* __restrict__ out, int CH) {
  int bc = blockIdx.x;
  int ch = bc % CH;
  __shared__ float tile[66 * 68];
  for (int i = threadIdx.x; i < 66 * 68; i += 256) tile[i] = 0.f;
  __syncthreads();
  const float* p = in + (size_t)bc * HW;
  for (int i = threadIdx.x; i < HW; i += 256) { int y = i >> 6, xx = i & 63; tile[(y + 1) * 68 + xx + 1] = p[i]; }
  __syncthreads();
  float w0 = w[ch * 9 + 0], w1 = w[ch * 9 + 1], w2 = w[ch * 9 + 2];
  float w3 = w[ch * 9 + 3], w4 = w[ch * 9 + 4], w5 = w[ch * 9 + 5];
  float w6 = w[ch * 9 + 6], w7 = w[ch * 9 + 7], w8 = w[ch * 9 + 8];
  float bb = bias[ch];
  float* op = out + (size_t)bc * HW;
  for (int i = threadIdx.x; i < HW; i += 256) {
    int y = i >> 6, xx = i & 63;
    const float* t = &tile[y * 68 + xx];
    float a = bb;
    a = fmaf(w0, t[0], a);   a = fmaf(w1, t[1], a);   a = fmaf(w2, t[2], a);
    a = fmaf(w3, t[68], a);  a = fmaf(w4, t[69], a);  a = fmaf(w5, t[70], a);
    a = fmaf(w6, t[136], a); a = fmaf(w7, t[137], a); a = fmaf(w8, t[138], a);
    op[i] = a;
  }
}

// ---------------- GDFN: dw3x3 on ch j and j+510, gelu(a1)*a2 ----------------
__global__ __launch_bounds__(256) void gdfn_dw_gate_kernel(const float* __restrict__ hid, const float* __restrict__ w,
                                                           const float* __restrict__ bias, float* __restrict__ gate) {
  int blk = blockIdx.x;           // b*HIDC + j
  int b = blk / HIDC, j = blk - b * HIDC;
  __shared__ float t1[66 * 68];
  __shared__ float t2[66 * 68];
  for (int i = threadIdx.x; i < 66 * 68; i += 256) { t1[i] = 0.f; t2[i] = 0.f; }
  __syncthreads();
  const float* p1 = hid + ((size_t)b * (2 * HIDC) + j) * HW;
  const float* p2 = p1 + (size_t)HIDC * HW;
  for (int i = threadIdx.x; i < HW; i += 256) {
    int y = i >> 6, xx = i & 63;
    t1[(y + 1) * 68 + xx + 1] = p1[i];
    t2[(y + 1) * 68 + xx + 1] = p2[i];
  }
  __syncthreads();
  int c1 = j, c2 = j + HIDC;
  float a0 = w[c1*9+0], a1w = w[c1*9+1], a2w = w[c1*9+2], a3 = w[c1*9+3], a4 = w[c1*9+4],
        a5 = w[c1*9+5], a6 = w[c1*9+6], a7 = w[c1*9+7], a8 = w[c1*9+8];
  float b0 = w[c2*9+0], b1 = w[c2*9+1], b2 = w[c2*9+2], b3 = w[c2*9+3], b4 = w[c2*9+4],
        b5 = w[c2*9+5], b6 = w[c2*9+6], b7 = w[c2*9+7], b8 = w[c2*9+8];
  float bi1 = bias[c1], bi2 = bias[c2];
  float* op = gate + ((size_t)b * HIDC + j) * HW;
  for (int i = threadIdx.x; i < HW; i += 256) {
    int y = i >> 6, xx = i & 63;
    const float* u = &t1[y * 68 + xx];
    const float* v = &t2[y * 68 + xx];
    float x1 = bi1;
    x1 = fmaf(a0, u[0], x1);   x1 = fmaf(a1w, u[1], x1);  x1 = fmaf(a2w, u[2], x1);
    x1 = fmaf(a3, u[68], x1);  x1 = fmaf(a4, u[69], x1);  x1 = fmaf(a5, u[70], x1);
    x1 = fmaf(a6, u[136], x1); x1 = fmaf(a7, u[137], x1); x1 = fmaf(a8, u[138], x1);
    float x2 = bi2;
    x2 = fmaf(b0, v[0], x2);   x2 = fmaf(b1, v[1], x2);   x2 = fmaf(b2, v[2], x2);
    x2 = fmaf(b3, v[68], x2);  x2 = fmaf(b4, v[69], x2);  x2 = fmaf(b5, v[70], x2);
    x2 = fmaf(b6, v[136], x2); x2 = fmaf(b7, v[137], x2); x2 = fmaf(b8, v[138], x2);
    float g = 0.5f * x1 * (1.f + erff(x1 * 0.70710678118654752f));
    op[i] = g * x2;
  }
}

// ---------------- q,k L2-normalize in-place over per-head channel dim ----------------
__global__ __launch_bounds__(256) void qknorm_kernel(float* __restrict__ qkv) {
  int gid = blockIdx.x * 256 + threadIdx.x;   // 8 * 4096
  int bh = gid >> 12, n = gid & 4095;
  int b = bh >> 2, h = bh & 3;
  float* qp = qkv + ((size_t)(b * (3 * DIMC) + h * DH)) * HW + n;
  float* kp = qp + (size_t)DIMC * HW;
  float ss = 0.f;
#pragma unroll
  for (int c = 0; c < DH; ++c) { float v = qp[(size_t)c * HW]; ss = fmaf(v, v, ss); }
  float sc = 1.f / fmaxf(sqrtf(ss), 1e-12f);
#pragma unroll
  for (int c = 0; c < DH; ++c) qp[(size_t)c * HW] *= sc;
  ss = 0.f;
#pragma unroll
  for (int c = 0; c < DH; ++c) { float v = kp[(size_t)c * HW]; ss = fmaf(v, v, ss); }
  sc = 1.f / fmaxf(sqrtf(ss), 1e-12f);
#pragma unroll
  for (int c = 0; c < DH; ++c) kp[(size_t)c * HW] *= sc;
}

// ---------------- flash attention, bf16 MFMA 16x16x32 ----------------
// grid: 512 = (b*4+h)*64 + ntile; block 256 (4 waves); N_TILE = M_TILE = 64, dh 48 padded to 64.
__global__ __launch_bounds__(256) void attn_kernel(const float* __restrict__ qkv, float* __restrict__ out,
                                                   const float* __restrict__ temp) {
  __shared__ __align__(16) __bf16 Qt[64 * 72];  // Qt[n][c]
  __shared__ __align__(16) __bf16 Kt[64 * 72];  // Kt[m][c]
  __shared__ __align__(16) __bf16 Vc[48 * 72];  // Vc[c][m]
  __shared__ __align__(16) __bf16 Pl[64 * 72];  // Pl[n][m]
  const int tid = threadIdx.x;
  const int lane = tid & 63;
  const int wv = tid >> 6;
  const int q4 = lane >> 4, l16 = lane & 15;
  const int bh = blockIdx.x >> 6, nt = blockIdx.x & 63;
  const int b = bh >> 2, h = bh & 3;
  const int n0 = nt * 64;
  const float T = temp[h];
  const float* Qg = qkv + ((size_t)(b * (3 * DIMC) + h * DH)) * HW;
  const float* Kg = Qg + (size_t)DIMC * HW;
  const float* Vg = Qg + (size_t)(2 * DIMC) * HW;

  // zero pad c in [48,64) once (re-stagings only touch c<48)
  for (int i = tid; i < 64 * 16; i += 256) {
    int n = i >> 4, c = 48 + (i & 15);
    Qt[n * 72 + c] = (__bf16)0.f;
    Kt[n * 72 + c] = (__bf16)0.f;
  }
  for (int i = tid; i < DH * 64; i += 256) {
    int c = i >> 6, n = i & 63;
    Qt[n * 72 + c] = (__bf16)Qg[(size_t)c * HW + n0 + n];
  }

  float m_run[4], l_run[4];
  f32x4 oacc[3];
#pragma unroll
  for (int r = 0; r < 4; ++r) { m_run[r] = -3.0e38f; l_run[r] = 0.f; }
#pragma unroll
  for (int ct = 0; ct < 3; ++ct) oacc[ct] = (f32x4){0.f, 0.f, 0.f, 0.f};

  const int arow = 16 * wv + l16;

  for (int mt = 0; mt < 64; ++mt) {
    const int m0 = mt * 64;
    __syncthreads();            // prior tile's reads of Kt/Vc complete
    for (int i = tid; i < DH * 64; i += 256) {
      int c = i >> 6, mm = i & 63;
      Kt[mm * 72 + c] = (__bf16)Kg[(size_t)c * HW + m0 + mm];
      Vc[c * 72 + mm] = (__bf16)Vg[(size_t)c * HW + m0 + mm];
    }
    __syncthreads();

    // S = Q^T K (per wave: 16-row strip x 64 cols)
    f32x4 sacc[4];
#pragma unroll
    for (int s = 0; s < 4; ++s) sacc[s] = (f32x4){0.f, 0.f, 0.f, 0.f};
#pragma unroll
    for (int ks = 0; ks < 2; ++ks) {
      bf16x8 af = *(const bf16x8*)&Qt[arow * 72 + 32 * ks + 8 * q4];
#pragma unroll
      for (int s = 0; s < 4; ++s) {
        bf16x8 bfr = *(const bf16x8*)&Kt[(16 * s + l16) * 72 + 32 * ks + 8 * q4];
        sacc[s] = __builtin_amdgcn_mfma_f32_16x16x32_bf16(af, bfr, sacc[s], 0, 0, 0);
      }
    }

    // online softmax; C-layout rows: 4*q4 + r, cols: l16 + 16*s
#pragma unroll
    for (int r = 0; r < 4; ++r) {
      float mloc = -3.0e38f;
#pragma unroll
      for (int s = 0; s < 4; ++s) mloc = fmaxf(mloc, sacc[s][r] * T);
      mloc = fmaxf(mloc, __shfl_xor(mloc, 1, 64));
      mloc = fmaxf(mloc, __shfl_xor(mloc, 2, 64));
      mloc = fmaxf(mloc, __shfl_xor(mloc, 4, 64));
      mloc = fmaxf(mloc, __shfl_xor(mloc, 8, 64));
      float mnew = fmaxf(m_run[r], mloc);
      float alpha = __expf(m_run[r] - mnew);
      float psum = 0.f;
      float pv[4];
#pragma unroll
      for (int s = 0; s < 4; ++s) { float p = __expf(sacc[s][r] * T - mnew); pv[s] = p; psum += p; }
      psum += __shfl_xor(psum, 1, 64);
      psum += __shfl_xor(psum, 2, 64);
      psum += __shfl_xor(psum, 4, 64);
      psum += __shfl_xor(psum, 8, 64);
      l_run[r] = l_run[r] * alpha + psum;
      m_run[r] = mnew;
#pragma unroll
      for (int ct = 0; ct < 3; ++ct) oacc[ct][r] *= alpha;
      int prow = 16 * wv + 4 * q4 + r;
#pragma unroll
      for (int s = 0; s < 4; ++s) Pl[prow * 72 + 16 * s + l16] = (__bf16)pv[s];
    }

    // O += P V^T  (A = P rows of own strip; B[k=m][col=c] = Vc[c][m])
#pragma unroll
    for (int ks = 0; ks < 2; ++ks) {
      bf16x8 pf = *(const bf16x8*)&Pl[arow * 72 + 32 * ks + 8 * q4];
#pragma unroll
      for (int ct = 0; ct < 3; ++ct) {
        bf16x8 vf = *(const bf16x8*)&Vc[(16 * ct + l16) * 72 + 32 * ks + 8 * q4];
        oacc[ct] = __builtin_amdgcn_mfma_f32_16x16x32_bf16(pf, vf, oacc[ct], 0, 0, 0);
      }
    }
  }

  // epilogue: out[b, h*48+c, n] = oacc / l
#pragma unroll
  for (int ct = 0; ct < 3; ++ct) {
    int c = l16 + 16 * ct;
#pragma unroll
    for (int r = 0; r < 4; ++r) {
      int n = n0 + 16 * wv + 4 * q4 + r;
      out[((size_t)(b * DIMC + h * DH + c)) * HW + n] = oacc[ct][r] / l_run[r];
    }
  }
}

extern "C" void kernel_launch(void* const* d_in, const int* in_sizes, int n_in,
                              void* d_out, int out_size, void* d_ws, size_t ws_size,
                              hipStream_t stream) {
  const float* x        = (const float*)d_in[0];
  const float* ln1_w    = (const float*)d_in[1];
  const float* ln1_b    = (const float*)d_in[2];
  const float* qkv_w    = (const float*)d_in[3];
  const float* qkv_b    = (const float*)d_in[4];
  const float* qkv_dw_w = (const float*)d_in[5];
  const float* qkv_dw_b = (const float*)d_in[6];
  const float* temperature = (const float*)d_in[7];
  const float* proj_w   = (const float*)d_in[8];
  const float* proj_b   = (const float*)d_in[9];
  const float* ln2_w    = (const float*)d_in[10];
  const float* ln2_b    = (const float*)d_in[11];
  const float* pin_w    = (const float*)d_in[12];
  const float* pin_b    = (const float*)d_in[13];
  const float* gdfn_dw_w = (const float*)d_in[14];
  const float* gdfn_dw_b = (const float*)d_in[15];
  const float* pout_w   = (const float*)d_in[16];
  const float* pout_b   = (const float*)d_in[17];
  float* out = (float*)d_out;
  float* ws = (float*)d_ws;

  // workspace layout (float offsets)
  float* wt_qkv  = ws + 0;         // 576*192   = 110592
  float* wt_proj = ws + 110592;    // 192*192   = 36864
  float* wt_pin  = ws + 147456;    // 1020*192  = 195840
  float* wt_pout = ws + 343296;    // 192*510   = 97920
  float* buf_ln  = ws + 441216;    // 2*192*4096  = 1572864
  float* buf_qkv = ws + 2014080;   // 2*576*4096  = 4718592
  float* buf_qdw = ws + 6732672;   // 2*576*4096  = 4718592
  float* buf_att = ws + 11451264;  // 2*192*4096  = 1572864 (end 13024128)
  float* buf_hid = buf_qkv;        // phase B reuse: 2*1020*4096 = 8355840 (ends 10369920)
  float* buf_gate = ws + 10369920; // 2*510*4096 = 4177920 (ends 14547840 floats = 58.2 MB)

  transpose_w_kernel<<<(110592 + 255) / 256, 256, 0, stream>>>(qkv_w, wt_qkv, 576, 192);
  transpose_w_kernel<<<(36864 + 255) / 256, 256, 0, stream>>>(proj_w, wt_proj, 192, 192);
  transpose_w_kernel<<<(195840 + 255) / 256, 256, 0, stream>>>(pin_w, wt_pin, 1020, 192);
  transpose_w_kernel<<<(97920 + 255) / 256, 256, 0, stream>>>(pout_w, wt_pout, 192, 510);

  // phase A: x1 = x + proj(attn(dw(conv(ln1(x)))))
  ln_kernel<<<2 * DIMC, 256, 0, stream>>>(x, ln1_w, ln1_b, buf_ln);
  conv1x1_kernel<<<dim3(16, 36, 2), 256, 0, stream>>>(buf_ln, wt_qkv, qkv_b, nullptr, buf_qkv, 576, 192);
  dwconv_kernel<<<2 * 576, 256, 0, stream>>>(buf_qkv, qkv_dw_w, qkv_dw_b, buf_qdw, 576);
  qknorm_kernel<<<128, 256, 0, stream>>>(buf_qdw);
  attn_kernel<<<512, 256, 0, stream>>>(buf_qdw, buf_att, temperature);
  conv1x1_kernel<<<dim3(16, 12, 2), 256, 0, stream>>>(buf_att, wt_proj, proj_b, x, out, 192, 192);

  // phase B: out += pout(gate(dw(pin(ln2(out)))))
  ln_kernel<<<2 * DIMC, 256, 0, stream>>>(out, ln2_w, ln2_b, buf_ln);
  conv1x1_kernel<<<dim3(16, 64, 2), 256, 0, stream>>>(buf_ln, wt_pin, pin_b, nullptr, buf_hid, 1020, 192);
  gdfn_dw_gate_kernel<<<2 * HIDC, 256, 0, stream>>>(buf_hid, gdfn_dw_w, gdfn_dw_b, buf_gate);
  conv1x1_kernel<<<dim3(16, 12, 2), 256, 0, stream>>>(buf_gate, wt_pout, pout_b, out, out, 192, 510);
}

// Round 2
// 488.716 us; speedup vs baseline: 1.4471x; 1.4471x over previous
//
#include <hip/hip_runtime.h>
#include <hip/hip_bf16.h>

typedef __bf16 bf16x8 __attribute__((ext_vector_type(8)));
typedef __bf16 bf16x4 __attribute__((ext_vector_type(4)));
typedef float f32x4 __attribute__((ext_vector_type(4)));

#define HW 4096
#define DIMC 192
#define NHEADS 4
#define DH 48
#define HIDC 510

// ---------------- W transpose: wt[c][o] = w[o][c] ----------------
__global__ void transpose_w_kernel(const float* __restrict__ w, float* __restrict__ wt, int O, int C) {
  int idx = blockIdx.x * 256 + threadIdx.x;
  if (idx >= O * C) return;
  int o = idx / C, c = idx - o * C;
  wt[(size_t)c * O + o] = w[idx];
}

// ---------------- LayerNorm2d: per (b,c) over HW ----------------
__global__ __launch_bounds__(256) void ln_kernel(const float* __restrict__ x, const float* __restrict__ w,
                                                 const float* __restrict__ b, float* __restrict__ out) {
  int bc = blockIdx.x;            // b*DIMC + c
  int c = bc % DIMC;
  const float* row = x + (size_t)bc * HW;
  float* orow = out + (size_t)bc * HW;
  float s = 0.f, s2 = 0.f;
  for (int i = threadIdx.x; i < HW; i += 256) { float v = row[i]; s += v; s2 = fmaf(v, v, s2); }
  __shared__ float red[8];
  for (int off = 32; off; off >>= 1) { s += __shfl_down(s, off, 64); s2 += __shfl_down(s2, off, 64); }
  int wid = threadIdx.x >> 6;
  if ((threadIdx.x & 63) == 0) { red[wid] = s; red[4 + wid] = s2; }
  __syncthreads();
  s = red[0] + red[1] + red[2] + red[3];
  s2 = red[4] + red[5] + red[6] + red[7];
  float mean = s * (1.f / HW);
  float var = s2 * (1.f / HW) - mean * mean;
  float rstd = rsqrtf(var + 1e-6f);
  float sc = rstd * w[c];
  float sh = b[c] - mean * sc;
  for (int i = threadIdx.x; i < HW; i += 256) orow[i] = fmaf(row[i], sc, sh);
}

// ---------------- conv1x1: out[b,o,n] = sum_c Wt[c][o] * X[b,c,n] (+bias, +res) ----------------
__global__ __launch_bounds__(256) void conv1x1_kernel(const float* __restrict__ X, const float* __restrict__ Wt,
                                                      const float* __restrict__ bias, const float* __restrict__ res,
                                                      float* __restrict__ out, int O, int C) {
  int b = blockIdx.z;
  int n = blockIdx.x * 256 + threadIdx.x;
  int o0 = blockIdx.y * 16;
  if (o0 + 16 > O) o0 = O - 16;
  const float* Xb = X + (size_t)b * C * HW + n;
  float acc[16];
#pragma unroll
  for (int i = 0; i < 16; ++i) acc[i] = 0.f;
#pragma unroll 4
  for (int c = 0; c < C; ++c) {
    float xv = Xb[(size_t)c * HW];
    const float* wr = Wt + (size_t)c * O + o0;
#pragma unroll
    for (int oo = 0; oo < 16; ++oo) acc[oo] = fmaf(wr[oo], xv, acc[oo]);
  }
  size_t base = (size_t)b * O * HW + (size_t)o0 * HW + n;
#pragma unroll
  for (int oo = 0; oo < 16; ++oo) {
    float v = acc[oo] + bias[o0 + oo];
    if (res) v += res[base + (size_t)oo * HW];
    out[base + (size_t)oo * HW] = v;
  }
}

// ---------------- depthwise 3x3, SAME, one (b,ch) plane per block ----------------
__global__ __launch_bounds__(256) void dwconv_kernel(const float* __restrict__ in, const float* __restrict__ w,
                                                     const float* __restrict__ bias, float* __restrict__ out, int CH) {
  int bc = blockIdx.x;
  int ch = bc % CH;
  __shared__ float tile[66 * 68];
  for (int i = threadIdx.x; i < 66 * 68; i += 256) tile[i] = 0.f;
  __syncthreads();
  const float* p = in + (size_t)bc * HW;
  for (int i = threadIdx.x; i < HW; i += 256) { int y = i >> 6, xx = i & 63; tile[(y + 1) * 68 + xx + 1] = p[i]; }
  __syncthreads();
  float w0 = w[ch * 9 + 0], w1 = w[ch * 9 + 1], w2 = w[ch * 9 + 2];
  float w3 = w[ch * 9 + 3], w4 = w[ch * 9 + 4], w5 = w[ch * 9 + 5];
  float w6 = w[ch * 9 + 6], w7 = w[ch * 9 + 7], w8 = w[ch * 9 + 8];
  float bb = bias[ch];
  float* op = out + (size_t)bc * HW;
  for (int i = threadIdx.x; i < HW; i += 256) {
    int y = i >> 6, xx = i & 63;
    const float* t = &tile[y * 68 + xx];
    float a = bb;
    a = fmaf(w0, t[0], a);   a = fmaf(w1, t[1], a);   a = fmaf(w2, t[2], a);
    a = fmaf(w3, t[68], a);  a = fmaf(w4, t[69], a);  a = fmaf(w5, t[70], a);
    a = fmaf(w6, t[136], a); a = fmaf(w7, t[137], a); a = fmaf(w8, t[138], a);
    op[i] = a;
  }
}

// ---------------- GDFN: dw3x3 on ch j and j+510, gelu(a1)*a2 ----------------
__global__ __launch_bounds__(256) void gdfn_dw_gate_kernel(const float* __restrict__ hid, const float* __restrict__ w,
                                                           const float* __restrict__ bias, float* __restrict__ gate) {
  int blk = blockIdx.x;           // b*HIDC + j
  int b = blk / HIDC, j = blk - b * HIDC;
  __shared__ float t1[66 * 68];
  __shared__ float t2[66 * 68];
  for (int i = threadIdx.x; i < 66 * 68; i += 256) { t1[i] = 0.f; t2[i] = 0.f; }
  __syncthreads();
  const float* p1 = hid + ((size_t)b * (2 * HIDC) + j) * HW;
  const float* p2 = p1 + (size_t)HIDC * HW;
  for (int i = threadIdx.x; i < HW; i += 256) {
    int y = i >> 6, xx = i & 63;
    t1[(y + 1) * 68 + xx + 1] = p1[i];
    t2[(y + 1) * 68 + xx + 1] = p2[i];
  }
  __syncthreads();
  int c1 = j, c2 = j + HIDC;
  float a0 = w[c1*9+0], a1w = w[c1*9+1], a2w = w[c1*9+2], a3 = w[c1*9+3], a4 = w[c1*9+4],
        a5 = w[c1*9+5], a6 = w[c1*9+6], a7 = w[c1*9+7], a8 = w[c1*9+8];
  float b0 = w[c2*9+0], b1 = w[c2*9+1], b2 = w[c2*9+2], b3 = w[c2*9+3], b4 = w[c2*9+4],
        b5 = w[c2*9+5], b6 = w[c2*9+6], b7 = w[c2*9+7], b8 = w[c2*9+8];
  float bi1 = bias[c1], bi2 = bias[c2];
  float* op = gate + ((size_t)b * HIDC + j) * HW;
  for (int i = threadIdx.x; i < HW; i += 256) {
    int y = i >> 6, xx = i & 63;
    const float* u = &t1[y * 68 + xx];
    const float* v = &t2[y * 68 + xx];
    float x1 = bi1;
    x1 = fmaf(a0, u[0], x1);   x1 = fmaf(a1w, u[1], x1);  x1 = fmaf(a2w, u[2], x1);
    x1 = fmaf(a3, u[68], x1);  x1 = fmaf(a4, u[69], x1);  x1 = fmaf(a5, u[70], x1);
    x1 = fmaf(a6, u[136], x1); x1 = fmaf(a7, u[137], x1); x1 = fmaf(a8, u[138], x1);
    float x2 = bi2;
    x2 = fmaf(b0, v[0], x2);   x2 = fmaf(b1, v[1], x2);   x2 = fmaf(b2, v[2], x2);
    x2 = fmaf(b3, v[68], x2);  x2 = fmaf(b4, v[69], x2);  x2 = fmaf(b5, v[70], x2);
    x2 = fmaf(b6, v[136], x2); x2 = fmaf(b7, v[137], x2); x2 = fmaf(b8, v[138], x2);
    float g = 0.5f * x1 * (1.f + erff(x1 * 0.70710678118654752f));
    op[i] = g * x2;
  }
}

// ---------------- prep: normalize q,k (fold temperature into q), emit bf16 n-major [bh][n][64] ----------------
__global__ __launch_bounds__(256) void prep_qk_kernel(const float* __restrict__ qdw, const float* __restrict__ temp,
                                                      __bf16* __restrict__ Qbf, __bf16* __restrict__ Kbf) {
  int gid = blockIdx.x * 256 + threadIdx.x;   // bh*4096 + n, 8*4096 total
  int bh = gid >> 12, n = gid & 4095;
  int b = bh >> 2, h = bh & 3;
  const float* qp = qdw + ((size_t)(b * (3 * DIMC) + h * DH)) * HW + n;
  const float* kp = qp + (size_t)DIMC * HW;
  float buf[DH];
  float ss = 0.f;
#pragma unroll
  for (int c = 0; c < DH; ++c) { buf[c] = qp[(size_t)c * HW]; ss = fmaf(buf[c], buf[c], ss); }
  float sc = temp[h] / fmaxf(sqrtf(ss), 1e-12f);
  __bf16 ob[64];
#pragma unroll
  for (int c = 0; c < DH; ++c) ob[c] = (__bf16)(buf[c] * sc);
#pragma unroll
  for (int c = DH; c < 64; ++c) ob[c] = (__bf16)0.f;
  __bf16* qd = Qbf + (size_t)gid * 64;
#pragma unroll
  for (int ch = 0; ch < 8; ++ch) *(bf16x8*)&qd[ch * 8] = *(bf16x8*)&ob[ch * 8];

  ss = 0.f;
#pragma unroll
  for (int c = 0; c < DH; ++c) { buf[c] = kp[(size_t)c * HW]; ss = fmaf(buf[c], buf[c], ss); }
  sc = 1.f / fmaxf(sqrtf(ss), 1e-12f);
#pragma unroll
  for (int c = 0; c < DH; ++c) ob[c] = (__bf16)(buf[c] * sc);
  __bf16* kd = Kbf + (size_t)gid * 64;
#pragma unroll
  for (int ch = 0; ch < 8; ++ch) *(bf16x8*)&kd[ch * 8] = *(bf16x8*)&ob[ch * 8];
}

// ---------------- prep: V fp32 [b][c][n] -> bf16 [bh][c][n] ----------------
__global__ __launch_bounds__(256) void prep_v_kernel(const float* __restrict__ qdw, __bf16* __restrict__ Vbf) {
  int i = blockIdx.x * 256 + threadIdx.x;     // over 48*1024
  int bh = blockIdx.y;
  int c = i >> 10, n4 = i & 1023;
  int b = bh >> 2, h = bh & 3;
  const float* src = qdw + ((size_t)(b * (3 * DIMC) + 2 * DIMC + h * DH + c)) * HW + n4 * 4;
  f32x4 v = *(const f32x4*)src;
  bf16x4 o = { (__bf16)v.x, (__bf16)v.y, (__bf16)v.z, (__bf16)v.w };
  *(bf16x4*)(Vbf + ((size_t)bh * DH + c) * HW + n4 * 4) = o;
}

// ---------------- flash attention v2: bf16 staged inputs, maxless softmax, MFMA 16x16x32 ----------------
// grid 512 = bh*64 + ntile; block 256 (4 waves); tiles 64x64; temperature pre-folded into Q.
__global__ __launch_bounds__(256) void attn_kernel(const __bf16* __restrict__ Qbf, const __bf16* __restrict__ Kbf,
                                                   const __bf16* __restrict__ Vbf, float* __restrict__ out) {
  __shared__ __align__(16) __bf16 Qt[64 * 72];  // Qt[n][c]
  __shared__ __align__(16) __bf16 Kt[64 * 72];  // Kt[m][c]
  __shared__ __align__(16) __bf16 Vc[48 * 72];  // Vc[c][m]
  __shared__ __align__(16) __bf16 Pl[64 * 72];  // Pl[n][m]
  __shared__ __align__(16) float Ot[48 * 68];   // Ot[c][n] epilogue transpose
  const int tid = threadIdx.x;
  const int lane = tid & 63;
  const int wv = tid >> 6;
  const int q4 = lane >> 4, l16 = lane & 15;
  const int bh = blockIdx.x >> 6, nt = blockIdx.x & 63;
  const int b = bh >> 2, h = bh & 3;
  const int n0 = nt * 64;
  const __bf16* Qg = Qbf + (size_t)bh * HW * 64;
  const __bf16* Kg = Kbf + (size_t)bh * HW * 64;
  const __bf16* Vg = Vbf + (size_t)bh * DH * HW;

  // stage Q tile: 64 rows x 64 cols bf16, 512 16B-chunks
  for (int i = tid; i < 512; i += 256) {
    int row = i >> 3, ch = i & 7;
    *(bf16x8*)&Qt[row * 72 + ch * 8] = *(const bf16x8*)&Qg[((size_t)(n0 + row)) * 64 + ch * 8];
  }

  float lpart[4] = {0.f, 0.f, 0.f, 0.f};
  f32x4 oacc[3];
#pragma unroll
  for (int ct = 0; ct < 3; ++ct) oacc[ct] = (f32x4){0.f, 0.f, 0.f, 0.f};

  const int arow = 16 * wv + l16;

  for (int mt = 0; mt < 64; ++mt) {
    const int m0 = mt * 64;
    __syncthreads();            // prior tile's reads of Kt/Vc complete
    for (int i = tid; i < 512; i += 256) {
      int row = i >> 3, ch = i & 7;
      *(bf16x8*)&Kt[row * 72 + ch * 8] = *(const bf16x8*)&Kg[((size_t)(m0 + row)) * 64 + ch * 8];
    }
    for (int i = tid; i < 384; i += 256) {
      int c = i >> 3, ch = i & 7;
      *(bf16x8*)&Vc[c * 72 + ch * 8] = *(const bf16x8*)&Vg[(size_t)c * HW + m0 + ch * 8];
    }
    __syncthreads();

    // S = Q K^T over c (temperature folded into Q)
    f32x4 sacc[4];
#pragma unroll
    for (int s = 0; s < 4; ++s) sacc[s] = (f32x4){0.f, 0.f, 0.f, 0.f};
#pragma unroll
    for (int ks = 0; ks < 2; ++ks) {
      bf16x8 af = *(const bf16x8*)&Qt[arow * 72 + 32 * ks + 8 * q4];
#pragma unroll
      for (int s = 0; s < 4; ++s) {
        bf16x8 bfr = *(const bf16x8*)&Kt[(16 * s + l16) * 72 + 32 * ks + 8 * q4];
        sacc[s] = __builtin_amdgcn_mfma_f32_16x16x32_bf16(af, bfr, sacc[s], 0, 0, 0);
      }
    }

    // maxless softmax: |S| <= T, exp cannot overflow; l-reduction deferred to epilogue
#pragma unroll
    for (int r = 0; r < 4; ++r) {
      float p0 = __expf(sacc[0][r]);
      float p1 = __expf(sacc[1][r]);
      float p2 = __expf(sacc[2][r]);
      float p3 = __expf(sacc[3][r]);
      lpart[r] += (p0 + p1) + (p2 + p3);
      int prow = 16 * wv + 4 * q4 + r;
      Pl[prow * 72 + l16]      = (__bf16)p0;
      Pl[prow * 72 + 16 + l16] = (__bf16)p1;
      Pl[prow * 72 + 32 + l16] = (__bf16)p2;
      Pl[prow * 72 + 48 + l16] = (__bf16)p3;
    }

    // O += P V^T (A = own strip's P rows; B[k=m][col=c] = Vc[c][m])
#pragma unroll
    for (int ks = 0; ks < 2; ++ks) {
      bf16x8 pf = *(const bf16x8*)&Pl[arow * 72 + 32 * ks + 8 * q4];
#pragma unroll
      for (int ct = 0; ct < 3; ++ct) {
        bf16x8 vf = *(const bf16x8*)&Vc[(16 * ct + l16) * 72 + 32 * ks + 8 * q4];
        oacc[ct] = __builtin_amdgcn_mfma_f32_16x16x32_bf16(pf, vf, oacc[ct], 0, 0, 0);
      }
    }
  }

  // reduce lpart across the 16 l16 lanes (each saw cols 16s+l16)
#pragma unroll
  for (int r = 0; r < 4; ++r) {
    float l = lpart[r];
    l += __shfl_xor(l, 1, 64);
    l += __shfl_xor(l, 2, 64);
    l += __shfl_xor(l, 4, 64);
    l += __shfl_xor(l, 8, 64);
    lpart[r] = 1.f / l;
  }
  // transpose O through LDS for coalesced stores
#pragma unroll
  for (int ct = 0; ct < 3; ++ct)
#pragma unroll
    for (int r = 0; r < 4; ++r)
      Ot[(16 * ct + l16) * 68 + 16 * wv + 4 * q4 + r] = oacc[ct][r] * lpart[r];
  __syncthreads();
  for (int i = tid; i < 768; i += 256) {
    int c = i >> 4, ch = i & 15;
    *(f32x4*)&out[((size_t)(b * DIMC + h * DH + c)) * HW + n0 + ch * 4] = *(const f32x4*)&Ot[c * 68 + ch * 4];
  }
}

extern "C" void kernel_launch(void* const* d_in, const int* in_sizes, int n_in,
                              void* d_out, int out_size, void* d_ws, size_t ws_size,
                              hipStream_t stream) {
  const float* x        = (const float*)d_in[0];
  const float* ln1_w    = (const float*)d_in[1];
  const float* ln1_b    = (const float*)d_in[2];
  const float* qkv_w    = (const float*)d_in[3];
  const float* qkv_b    = (const float*)d_in[4];
  const float* qkv_dw_w = (const float*)d_in[5];
  const float* qkv_dw_b = (const float*)d_in[6];
  const float* temperature = (const float*)d_in[7];
  const float* proj_w   = (const float*)d_in[8];
  const float* proj_b   = (const float*)d_in[9];
  const float* ln2_w    = (const float*)d_in[10];
  const float* ln2_b    = (const float*)d_in[11];
  const float* pin_w    = (const float*)d_in[12];
  const float* pin_b    = (const float*)d_in[13];
  const float* gdfn_dw_w = (const float*)d_in[14];
  const float* gdfn_dw_b = (const float*)d_in[15];
  const float* pout_w   = (const float*)d_in[16];
  const float* pout_b   = (const float*)d_in[17];
  float* out = (float*)d_out;
  float* ws = (float*)d_ws;

  // workspace layout (float offsets)
  float* wt_qkv  = ws + 0;         // 576*192
  float* wt_proj = ws + 110592;    // 192*192
  float* wt_pin  = ws + 147456;    // 1020*192
  float* wt_pout = ws + 343296;    // 192*510
  float* buf_ln  = ws + 441216;    // 2*192*4096
  float* buf_qkv = ws + 2014080;   // 2*576*4096 (reused: bf16 Q/K/V after dwconv; buf_hid in phase B)
  float* buf_qdw = ws + 6732672;   // 2*576*4096
  float* buf_att = ws + 11451264;  // 2*192*4096
  float* buf_hid = buf_qkv;
  float* buf_gate = ws + 10369920; // 2*510*4096

  // bf16 attention operands carved from buf_qkv (free after dwconv)
  __bf16* Qbf = (__bf16*)buf_qkv;                       // 8*4096*64 bf16
  __bf16* Kbf = Qbf + (size_t)8 * HW * 64;              // 8*4096*64 bf16
  __bf16* Vbf = Kbf + (size_t)8 * HW * 64;              // 8*48*4096 bf16 (11.25 MB total <= 18.9 MB region)

  transpose_w_kernel<<<(110592 + 255) / 256, 256, 0, stream>>>(qkv_w, wt_qkv, 576, 192);
  transpose_w_kernel<<<(36864 + 255) / 256, 256, 0, stream>>>(proj_w, wt_proj, 192, 192);
  transpose_w_kernel<<<(195840 + 255) / 256, 256, 0, stream>>>(pin_w, wt_pin, 1020, 192);
  transpose_w_kernel<<<(97920 + 255) / 256, 256, 0, stream>>>(pout_w, wt_pout, 192, 510);

  // phase A: x1 = x + proj(attn(dw(conv(ln1(x)))))
  ln_kernel<<<2 * DIMC, 256, 0, stream>>>(x, ln1_w, ln1_b, buf_ln);
  conv1x1_kernel<<<dim3(16, 36, 2), 256, 0, stream>>>(buf_ln, wt_qkv, qkv_b, nullptr, buf_qkv, 576, 192);
  dwconv_kernel<<<2 * 576, 256, 0, stream>>>(buf_qkv, qkv_dw_w, qkv_dw_b, buf_qdw, 576);
  prep_v_kernel<<<dim3(192, 8), 256, 0, stream>>>(buf_qdw, Vbf);
  prep_qk_kernel<<<128, 256, 0, stream>>>(buf_qdw, temperature, Qbf, Kbf);
  attn_kernel<<<512, 256, 0, stream>>>(Qbf, Kbf, Vbf, buf_att);
  conv1x1_kernel<<<dim3(16, 12, 2), 256, 0, stream>>>(buf_att, wt_proj, proj_b, x, out, 192, 192);

  // phase B: out += pout(gate(dw(pin(ln2(out)))))
  ln_kernel<<<2 * DIMC, 256, 0, stream>>>(out, ln2_w, ln2_b, buf_ln);
  conv1x1_kernel<<<dim3(16, 64, 2), 256, 0, stream>>>(buf_ln, wt_pin, pin_b, nullptr, buf_hid, 1020, 192);
  gdfn_dw_gate_kernel<<<2 * HIDC, 256, 0, stream>>>(buf_hid, gdfn_dw_w, gdfn_dw_b, buf_gate);
  conv1x1_kernel<<<dim3(16, 12, 2), 256, 0, stream>>>(buf_gate, wt_pout, pout_b, out, out, 192, 510);
}

// Round 3
// 297.079 us; speedup vs baseline: 2.3806x; 1.6451x over previous
//
#include <hip/hip_runtime.h>
#include <hip/hip_bf16.h>

typedef __bf16 bf16x8 __attribute__((ext_vector_type(8)));
typedef __bf16 bf16x4 __attribute__((ext_vector_type(4)));
typedef float f32x4 __attribute__((ext_vector_type(4)));

#define HW 4096
#define DIMC 192
#define NHEADS 4
#define DH 48
#define HIDC 510

// ---------------- weight convert fp32 [O][C] -> bf16 [O][Cp] (zero-pad) ----------------
__global__ void wcvt_kernel(const float* __restrict__ w, __bf16* __restrict__ wb, int O, int C, int Cp) {
  int idx = blockIdx.x * 256 + threadIdx.x;
  if (idx >= O * Cp) return;
  int o = idx / Cp, c = idx - o * Cp;
  wb[idx] = (c < C) ? (__bf16)w[o * C + c] : (__bf16)0.f;
}

// ---------------- LN stats: per (b,c) -> sc = rstd*w, sh = b - mean*sc ----------------
__global__ __launch_bounds__(256) void ln_stats_kernel(const float* __restrict__ x, const float* __restrict__ w,
                                                       const float* __restrict__ b, float* __restrict__ sc,
                                                       float* __restrict__ sh) {
  int bc = blockIdx.x;            // b*DIMC + c
  int c = bc % DIMC;
  const float* row = x + (size_t)bc * HW;
  float s = 0.f, s2 = 0.f;
  for (int i = threadIdx.x; i < HW; i += 256) { float v = row[i]; s += v; s2 = fmaf(v, v, s2); }
  __shared__ float red[8];
  for (int off = 32; off; off >>= 1) { s += __shfl_down(s, off, 64); s2 += __shfl_down(s2, off, 64); }
  int wid = threadIdx.x >> 6;
  if ((threadIdx.x & 63) == 0) { red[wid] = s; red[4 + wid] = s2; }
  __syncthreads();
  if (threadIdx.x == 0) {
    s = red[0] + red[1] + red[2] + red[3];
    s2 = red[4] + red[5] + red[6] + red[7];
    float mean = s * (1.f / HW);
    float var = s2 * (1.f / HW) - mean * mean;
    float rstd = rsqrtf(var + 1e-6f);
    float scv = rstd * w[c];
    sc[bc] = scv;
    sh[bc] = b[c] - mean * scv;
  }
}

// ---------------- LN apply + transpose-convert: fp32 [b][192][n] -> bf16 Xt[(b*4096+n)][192] ----------------
// grid (64 n-tiles, 6 c-tiles, 2 b), block 256
__global__ __launch_bounds__(256) void ln_apply_t_kernel(const float* __restrict__ x, const float* __restrict__ sc,
                                                         const float* __restrict__ sh, __bf16* __restrict__ Xt) {
  int n0 = blockIdx.x * 64, c0 = blockIdx.y * 32, b = blockIdx.z;
  int t = threadIdx.x;
  int n = t & 63, cs = c0 + (t >> 6) * 8;
  __bf16 ob[8];
#pragma unroll
  for (int cc = 0; cc < 8; ++cc) {
    int c = cs + cc;
    float v = fmaf(x[((size_t)(b * DIMC + c)) * HW + n0 + n], sc[b * DIMC + c], sh[b * DIMC + c]);
    ob[cc] = (__bf16)v;
  }
  *(bf16x8*)&Xt[((size_t)((b << 12) + n0 + n)) * DIMC + cs] = *(bf16x8*)ob;
}

// ---------------- bf16 MFMA GEMM: out[b][o][n] = sum_c A[o][c] * Xt[(b*4096+n)][c] + bias ----------------
// A bf16 [O][Cs] (row-major, Cs padded-mult-of-32), Bt bf16 [8192][Cs].
// mode 0: fp32 out; 1: bf16 out; 2: fp32 out + fp32 residual.
// grid (64 n-tiles of 128, ceil(O/64)), block 256 (4 waves, each 16 o-rows x 128 n)
__global__ __launch_bounds__(256) void gemm_kernel(const __bf16* __restrict__ A, const __bf16* __restrict__ Bt,
                                                   const float* __restrict__ bias, const float* __restrict__ res,
                                                   float* __restrict__ outf, __bf16* __restrict__ outb,
                                                   int O, int Cs, int mode) {
  __shared__ __align__(16) __bf16 Asub[64 * 40];
  __shared__ __align__(16) __bf16 Bsub[128 * 40];
  const int t = threadIdx.x;
  const int lane = t & 63, wv = t >> 6;
  const int q4 = lane >> 4, l16 = lane & 15;
  int o0 = blockIdx.y * 64;
  if (o0 + 64 > O) o0 = O - 64;
  const int ntot0 = blockIdx.x * 128;
  const int b = ntot0 >> 12;

  f32x4 acc[8];
#pragma unroll
  for (int nt = 0; nt < 8; ++nt) acc[nt] = (f32x4){0.f, 0.f, 0.f, 0.f};

  for (int c0 = 0; c0 < Cs; c0 += 32) {
    __syncthreads();
    // stage A: 64 rows x 32 c = 256 chunks
    *(bf16x8*)&Asub[(t >> 2) * 40 + (t & 3) * 8] =
        *(const bf16x8*)&A[((size_t)(o0 + (t >> 2))) * Cs + c0 + (t & 3) * 8];
    // stage B: 128 rows x 32 c = 512 chunks
#pragma unroll
    for (int j = 0; j < 2; ++j) {
      int id = t + 256 * j;
      *(bf16x8*)&Bsub[(id >> 2) * 40 + (id & 3) * 8] =
          *(const bf16x8*)&Bt[((size_t)(ntot0 + (id >> 2))) * Cs + c0 + (id & 3) * 8];
    }
    __syncthreads();
    bf16x8 af = *(const bf16x8*)&Asub[(16 * wv + l16) * 40 + 8 * q4];
#pragma unroll
    for (int nt = 0; nt < 8; ++nt) {
      bf16x8 bfr = *(const bf16x8*)&Bsub[(16 * nt + l16) * 40 + 8 * q4];
      acc[nt] = __builtin_amdgcn_mfma_f32_16x16x32_bf16(af, bfr, acc[nt], 0, 0, 0);
    }
  }

  // epilogue: value at (o = o0+16wv+4q4+r, n = ntot0 + 16nt + l16)
  float bvals[4];
#pragma unroll
  for (int r = 0; r < 4; ++r) bvals[r] = bias[o0 + 16 * wv + 4 * q4 + r];
#pragma unroll
  for (int nt = 0; nt < 8; ++nt) {
    int n_in_b = (ntot0 & 4095) + 16 * nt + l16;
#pragma unroll
    for (int r = 0; r < 4; ++r) {
      int o = o0 + 16 * wv + 4 * q4 + r;
      size_t addr = ((size_t)(b * O + o)) * HW + n_in_b;
      float v = acc[nt][r] + bvals[r];
      if (mode == 2) { outf[addr] = v + res[addr]; }
      else if (mode == 0) { outf[addr] = v; }
      else { outb[addr] = (__bf16)v; }
    }
  }
}

// ---------------- depthwise 3x3, SAME, one (b,ch) plane per block (fp32) ----------------
__global__ __launch_bounds__(256) void dwconv_kernel(const float* __restrict__ in, const float* __restrict__ w,
                                                     const float* __restrict__ bias, float* __restrict__ out, int CH) {
  int bc = blockIdx.x;
  int ch = bc % CH;
  __shared__ float tile[66 * 68];
  for (int i = threadIdx.x; i < 66 * 68; i += 256) tile[i] = 0.f;
  __syncthreads();
  const float* p = in + (size_t)bc * HW;
  for (int i = threadIdx.x; i < HW; i += 256) { int y = i >> 6, xx = i & 63; tile[(y + 1) * 68 + xx + 1] = p[i]; }
  __syncthreads();
  float w0 = w[ch * 9 + 0], w1 = w[ch * 9 + 1], w2 = w[ch * 9 + 2];
  float w3 = w[ch * 9 + 3], w4 = w[ch * 9 + 4], w5 = w[ch * 9 + 5];
  float w6 = w[ch * 9 + 6], w7 = w[ch * 9 + 7], w8 = w[ch * 9 + 8];
  float bb = bias[ch];
  float* op = out + (size_t)bc * HW;
  for (int i = threadIdx.x; i < HW; i += 256) {
    int y = i >> 6, xx = i & 63;
    const float* tt = &tile[y * 68 + xx];
    float a = bb;
    a = fmaf(w0, tt[0], a);   a = fmaf(w1, tt[1], a);   a = fmaf(w2, tt[2], a);
    a = fmaf(w3, tt[68], a);  a = fmaf(w4, tt[69], a);  a = fmaf(w5, tt[70], a);
    a = fmaf(w6, tt[136], a); a = fmaf(w7, tt[137], a); a = fmaf(w8, tt[138], a);
    op[i] = a;
  }
}

// ---------------- GDFN: dw3x3 on bf16 hid ch j and j+510, gelu(a1)*a2 -> bf16 gate ----------------
__global__ __launch_bounds__(256) void gdfn_dw_gate_kernel(const __bf16* __restrict__ hid, const float* __restrict__ w,
                                                           const float* __restrict__ bias, __bf16* __restrict__ gate) {
  int blk = blockIdx.x;           // b*HIDC + j
  int b = blk / HIDC, j = blk - b * HIDC;
  __shared__ float t1[66 * 68];
  __shared__ float t2[66 * 68];
  for (int i = threadIdx.x; i < 66 * 68; i += 256) { t1[i] = 0.f; t2[i] = 0.f; }
  __syncthreads();
  const __bf16* p1 = hid + ((size_t)b * (2 * HIDC) + j) * HW;
  const __bf16* p2 = p1 + (size_t)HIDC * HW;
  for (int i = threadIdx.x; i < HW; i += 256) {
    int y = i >> 6, xx = i & 63;
    t1[(y + 1) * 68 + xx + 1] = (float)p1[i];
    t2[(y + 1) * 68 + xx + 1] = (float)p2[i];
  }
  __syncthreads();
  int c1 = j, c2 = j + HIDC;
  float a0 = w[c1*9+0], a1w = w[c1*9+1], a2w = w[c1*9+2], a3 = w[c1*9+3], a4 = w[c1*9+4],
        a5 = w[c1*9+5], a6 = w[c1*9+6], a7 = w[c1*9+7], a8 = w[c1*9+8];
  float b0 = w[c2*9+0], b1 = w[c2*9+1], b2 = w[c2*9+2], b3 = w[c2*9+3], b4 = w[c2*9+4],
        b5 = w[c2*9+5], b6 = w[c2*9+6], b7 = w[c2*9+7], b8 = w[c2*9+8];
  float bi1 = bias[c1], bi2 = bias[c2];
  __bf16* op = gate + ((size_t)b * HIDC + j) * HW;
  for (int i = threadIdx.x; i < HW; i += 256) {
    int y = i >> 6, xx = i & 63;
    const float* u = &t1[y * 68 + xx];
    const float* v = &t2[y * 68 + xx];
    float x1 = bi1;
    x1 = fmaf(a0, u[0], x1);   x1 = fmaf(a1w, u[1], x1);  x1 = fmaf(a2w, u[2], x1);
    x1 = fmaf(a3, u[68], x1);  x1 = fmaf(a4, u[69], x1);  x1 = fmaf(a5, u[70], x1);
    x1 = fmaf(a6, u[136], x1); x1 = fmaf(a7, u[137], x1); x1 = fmaf(a8, u[138], x1);
    float x2 = bi2;
    x2 = fmaf(b0, v[0], x2);   x2 = fmaf(b1, v[1], x2);   x2 = fmaf(b2, v[2], x2);
    x2 = fmaf(b3, v[68], x2);  x2 = fmaf(b4, v[69], x2);  x2 = fmaf(b5, v[70], x2);
    x2 = fmaf(b6, v[136], x2); x2 = fmaf(b7, v[137], x2); x2 = fmaf(b8, v[138], x2);
    float g = 0.5f * x1 * (1.f + erff(x1 * 0.70710678118654752f));
    op[i] = (__bf16)(g * x2);
  }
}

// ---------------- gate bf16 [b][510][n] -> Xt bf16 [(b*4096+n)][512] (pad cols 510,511 = 0) ----------------
// grid (64 n-tiles, 16 c-tiles, 2 b)
__global__ __launch_bounds__(256) void transpose_gate_kernel(const __bf16* __restrict__ gate, __bf16* __restrict__ Xt) {
  int n0 = blockIdx.x * 64, c0 = blockIdx.y * 32, b = blockIdx.z;
  int t = threadIdx.x;
  int n = t & 63, cs = c0 + (t >> 6) * 8;
  __bf16 ob[8];
#pragma unroll
  for (int cc = 0; cc < 8; ++cc) {
    int c = cs + cc;
    ob[cc] = (c < HIDC) ? gate[((size_t)(b * HIDC + c)) * HW + n0 + n] : (__bf16)0.f;
  }
  *(bf16x8*)&Xt[((size_t)((b << 12) + n0 + n)) * 512 + cs] = *(bf16x8*)ob;
}

// ---------------- prep: normalize q,k (fold temperature into q), emit bf16 n-major [bh][n][64] ----------------
__global__ __launch_bounds__(256) void prep_qk_kernel(const float* __restrict__ qdw, const float* __restrict__ temp,
                                                      __bf16* __restrict__ Qbf, __bf16* __restrict__ Kbf) {
  int gid = blockIdx.x * 256 + threadIdx.x;   // bh*4096 + n
  int bh = gid >> 12, n = gid & 4095;
  int b = bh >> 2, h = bh & 3;
  const float* qp = qdw + ((size_t)(b * (3 * DIMC) + h * DH)) * HW + n;
  const float* kp = qp + (size_t)DIMC * HW;
  float buf[DH];
  float ss = 0.f;
#pragma unroll
  for (int c = 0; c < DH; ++c) { buf[c] = qp[(size_t)c * HW]; ss = fmaf(buf[c], buf[c], ss); }
  float sc = temp[h] / fmaxf(sqrtf(ss), 1e-12f);
  __bf16 ob[64];
#pragma unroll
  for (int c = 0; c < DH; ++c) ob[c] = (__bf16)(buf[c] * sc);
#pragma unroll
  for (int c = DH; c < 64; ++c) ob[c] = (__bf16)0.f;
  __bf16* qd = Qbf + (size_t)gid * 64;
#pragma unroll
  for (int ch = 0; ch < 8; ++ch) *(bf16x8*)&qd[ch * 8] = *(bf16x8*)&ob[ch * 8];

  ss = 0.f;
#pragma unroll
  for (int c = 0; c < DH; ++c) { buf[c] = kp[(size_t)c * HW]; ss = fmaf(buf[c], buf[c], ss); }
  sc = 1.f / fmaxf(sqrtf(ss), 1e-12f);
#pragma unroll
  for (int c = 0; c < DH; ++c) ob[c] = (__bf16)(buf[c] * sc);
  __bf16* kd = Kbf + (size_t)gid * 64;
#pragma unroll
  for (int ch = 0; ch < 8; ++ch) *(bf16x8*)&kd[ch * 8] = *(bf16x8*)&ob[ch * 8];
}

// ---------------- prep: V fp32 [b][c][n] -> bf16 [bh][c][n] ----------------
__global__ __launch_bounds__(256) void prep_v_kernel(const float* __restrict__ qdw, __bf16* __restrict__ Vbf) {
  int i = blockIdx.x * 256 + threadIdx.x;     // over 48*1024
  int bh = blockIdx.y;
  int c = i >> 10, n4 = i & 1023;
  int b = bh >> 2, h = bh & 3;
  const float* src = qdw + ((size_t)(b * (3 * DIMC) + 2 * DIMC + h * DH + c)) * HW + n4 * 4;
  f32x4 v = *(const f32x4*)src;
  bf16x4 o = { (__bf16)v.x, (__bf16)v.y, (__bf16)v.z, (__bf16)v.w };
  *(bf16x4*)(Vbf + ((size_t)bh * DH + c) * HW + n4 * 4) = o;
}

// ---------------- flash attention split-K: 4 chunks of 16 m-tiles; unnormalized partials ----------------
// grid 2048 = chunk*512 + bh*64 + nt; block 256 (4 waves). Partial: O[64n][48c] fp32 + l[64n].
__global__ __launch_bounds__(256) void attn_split_kernel(const __bf16* __restrict__ Qbf, const __bf16* __restrict__ Kbf,
                                                         const __bf16* __restrict__ Vbf, float* __restrict__ part) {
  __shared__ __align__(16) __bf16 Qt[64 * 72];  // Qt[n][c]
  __shared__ __align__(16) __bf16 Kt[64 * 72];  // Kt[m][c]
  __shared__ __align__(16) __bf16 Vc[48 * 72];  // Vc[c][m]
  __shared__ __align__(16) __bf16 Pl[64 * 72];  // Pl[n][m]
  const int tid = threadIdx.x;
  const int lane = tid & 63;
  const int wv = tid >> 6;
  const int q4 = lane >> 4, l16 = lane & 15;
  const int bid = blockIdx.x;
  const int chunk = bid >> 9, rest = bid & 511;
  const int bh = rest >> 6, nt = rest & 63;
  const int n0 = nt * 64;
  const __bf16* Qg = Qbf + (size_t)bh * HW * 64;
  const __bf16* Kg = Kbf + (size_t)bh * HW * 64;
  const __bf16* Vg = Vbf + (size_t)bh * DH * HW;

  for (int i = tid; i < 512; i += 256) {
    int row = i >> 3, ch = i & 7;
    *(bf16x8*)&Qt[row * 72 + ch * 8] = *(const bf16x8*)&Qg[((size_t)(n0 + row)) * 64 + ch * 8];
  }

  float lpart[4] = {0.f, 0.f, 0.f, 0.f};
  f32x4 oacc[3];
#pragma unroll
  for (int ct = 0; ct < 3; ++ct) oacc[ct] = (f32x4){0.f, 0.f, 0.f, 0.f};

  const int arow = 16 * wv + l16;

  for (int mt = chunk * 16; mt < chunk * 16 + 16; ++mt) {
    const int m0 = mt * 64;
    __syncthreads();
    for (int i = tid; i < 512; i += 256) {
      int row = i >> 3, ch = i & 7;
      *(bf16x8*)&Kt[row * 72 + ch * 8] = *(const bf16x8*)&Kg[((size_t)(m0 + row)) * 64 + ch * 8];
    }
    for (int i = tid; i < 384; i += 256) {
      int c = i >> 3, ch = i & 7;
      *(bf16x8*)&Vc[c * 72 + ch * 8] = *(const bf16x8*)&Vg[(size_t)c * HW + m0 + ch * 8];
    }
    __syncthreads();

    f32x4 sacc[4];
#pragma unroll
    for (int s = 0; s < 4; ++s) sacc[s] = (f32x4){0.f, 0.f, 0.f, 0.f};
#pragma unroll
    for (int ks = 0; ks < 2; ++ks) {
      bf16x8 af = *(const bf16x8*)&Qt[arow * 72 + 32 * ks + 8 * q4];
#pragma unroll
      for (int s = 0; s < 4; ++s) {
        bf16x8 bfr = *(const bf16x8*)&Kt[(16 * s + l16) * 72 + 32 * ks + 8 * q4];
        sacc[s] = __builtin_amdgcn_mfma_f32_16x16x32_bf16(af, bfr, sacc[s], 0, 0, 0);
      }
    }

    // maxless softmax (|S| <= temp), deferred l-reduction
#pragma unroll
    for (int r = 0; r < 4; ++r) {
      float p0 = __expf(sacc[0][r]);
      float p1 = __expf(sacc[1][r]);
      float p2 = __expf(sacc[2][r]);
      float p3 = __expf(sacc[3][r]);
      lpart[r] += (p0 + p1) + (p2 + p3);
      int prow = 16 * wv + 4 * q4 + r;
      Pl[prow * 72 + l16]      = (__bf16)p0;
      Pl[prow * 72 + 16 + l16] = (__bf16)p1;
      Pl[prow * 72 + 32 + l16] = (__bf16)p2;
      Pl[prow * 72 + 48 + l16] = (__bf16)p3;
    }

#pragma unroll
    for (int ks = 0; ks < 2; ++ks) {
      bf16x8 pf = *(const bf16x8*)&Pl[arow * 72 + 32 * ks + 8 * q4];
#pragma unroll
      for (int ct = 0; ct < 3; ++ct) {
        bf16x8 vf = *(const bf16x8*)&Vc[(16 * ct + l16) * 72 + 32 * ks + 8 * q4];
        oacc[ct] = __builtin_amdgcn_mfma_f32_16x16x32_bf16(pf, vf, oacc[ct], 0, 0, 0);
      }
    }
  }

  // write partials: O[n_local][c] + l[n_local]
  size_t pbase = (size_t)bid * 3136;
#pragma unroll
  for (int r = 0; r < 4; ++r) {
    float l = lpart[r];
    l += __shfl_xor(l, 1, 64);
    l += __shfl_xor(l, 2, 64);
    l += __shfl_xor(l, 4, 64);
    l += __shfl_xor(l, 8, 64);
    int nl = 16 * wv + 4 * q4 + r;
    if (l16 == 0) part[pbase + 3072 + nl] = l;
#pragma unroll
    for (int ct = 0; ct < 3; ++ct)
      part[pbase + (size_t)nl * 48 + 16 * ct + l16] = oacc[ct][r];
  }
}

// ---------------- merge 4 chunks + normalize -> Xt_att bf16 [(b*4096+n)][192] ----------------
// grid 512 = bh*64 + nt
__global__ __launch_bounds__(256) void attn_merge_kernel(const float* __restrict__ part, __bf16* __restrict__ Xt) {
  const int bid = blockIdx.x;
  const int bh = bid >> 6, nt = bid & 63;
  const int b = bh >> 2, h = bh & 3;
  const int n0 = nt * 64;
  const int t = threadIdx.x;
  __shared__ float linv[64];
  if (t < 64) {
    float s = 0.f;
#pragma unroll
    for (int ch = 0; ch < 4; ++ch) s += part[((size_t)(ch * 512 + bid)) * 3136 + 3072 + t];
    linv[t] = 1.f / s;
  }
  __syncthreads();
#pragma unroll
  for (int j = 0; j < 3; ++j) {
    int id = t + 256 * j;          // 768 f32x4 chunks: n = id/12, c4 = (id%12)*4
    int n = id / 12, cc = (id - n * 12) * 4;
    f32x4 s = (f32x4){0.f, 0.f, 0.f, 0.f};
#pragma unroll
    for (int ch = 0; ch < 4; ++ch) s += *(const f32x4*)&part[((size_t)(ch * 512 + bid)) * 3136 + (size_t)n * 48 + cc];
    float li = linv[n];
    bf16x4 ov = { (__bf16)(s.x * li), (__bf16)(s.y * li), (__bf16)(s.z * li), (__bf16)(s.w * li) };
    *(bf16x4*)&Xt[((size_t)((b << 12) + n0 + n)) * DIMC + h * DH + cc] = ov;
  }
}

extern "C" void kernel_launch(void* const* d_in, const int* in_sizes, int n_in,
                              void* d_out, int out_size, void* d_ws, size_t ws_size,
                              hipStream_t stream) {
  const float* x        = (const float*)d_in[0];
  const float* ln1_w    = (const float*)d_in[1];
  const float* ln1_b    = (const float*)d_in[2];
  const float* qkv_w    = (const float*)d_in[3];
  const float* qkv_b    = (const float*)d_in[4];
  const float* qkv_dw_w = (const float*)d_in[5];
  const float* qkv_dw_b = (const float*)d_in[6];
  const float* temperature = (const float*)d_in[7];
  const float* proj_w   = (const float*)d_in[8];
  const float* proj_b   = (const float*)d_in[9];
  const float* ln2_w    = (const float*)d_in[10];
  const float* ln2_b    = (const float*)d_in[11];
  const float* pin_w    = (const float*)d_in[12];
  const float* pin_b    = (const float*)d_in[13];
  const float* gdfn_dw_w = (const float*)d_in[14];
  const float* gdfn_dw_b = (const float*)d_in[15];
  const float* pout_w   = (const float*)d_in[16];
  const float* pout_b   = (const float*)d_in[17];
  float* out = (float*)d_out;
  float* ws = (float*)d_ws;

  // ---- workspace layout (float offsets) ----
  __bf16* wb_qkv  = (__bf16*)(ws + 0);          // 576*192 bf16 = 55296 f
  __bf16* wb_proj = (__bf16*)(ws + 55296);      // 192*192 -> 18432 f
  __bf16* wb_pin  = (__bf16*)(ws + 73728);      // 1020*192 -> 97920 f
  __bf16* wb_pout = (__bf16*)(ws + 171648);     // 192*512 -> 49152 f
  float* sc1 = ws + 220800;                     // 384
  float* sh1 = ws + 221184;                     // 384
  float* sc2 = ws + 221568;                     // 384
  float* sh2 = ws + 221952;                     // 384 -> ends 222336
  // region3 @222336 (2,883,584 f): Xt1 (786,432 f) then Q/K/Vbf
  __bf16* Xt1 = (__bf16*)(ws + 222336);
  __bf16* Qbf = (__bf16*)(ws + 222336);         // 1,048,576 f
  __bf16* Kbf = (__bf16*)(ws + 1270912);        // 1,048,576 f
  __bf16* Vbf = (__bf16*)(ws + 2319488);        // 786,432 f -> ends 3,105,920
  // region1 @3,105,920 (4,718,592 f): qkv fp32 / Xt_att bf16 / hid bf16
  float*  qkvbuf = ws + 3105920;
  __bf16* Xt_att = (__bf16*)(ws + 3105920);
  __bf16* hid    = (__bf16*)(ws + 3105920);
  // region2 @7,824,512 (4,718,592 f): qdw fp32; later gate + Xt_gate; Opart spans 7,824,512..14,247,040
  float*  qdw     = ws + 7824512;
  float*  Opart   = ws + 7824512;               // 4*512*3136 = 6,422,528 f (after qdw dead)
  __bf16* gate    = (__bf16*)(ws + 7824512);    // 2,088,960 f (after Opart dead)
  __bf16* Xt_gate = (__bf16*)(ws + 9913472);    // 2,097,152 f -> ends 12,010,624
  __bf16* Xt2     = (__bf16*)(ws + 12543104);   // 786,432 f -> ends 13,329,536 (Opart dead by then)
  // total 14,247,040 f = 57.0 MB

  // weight converts
  wcvt_kernel<<<(576 * 192 + 255) / 256, 256, 0, stream>>>(qkv_w, wb_qkv, 576, 192, 192);
  wcvt_kernel<<<(192 * 192 + 255) / 256, 256, 0, stream>>>(proj_w, wb_proj, 192, 192, 192);
  wcvt_kernel<<<(1020 * 192 + 255) / 256, 256, 0, stream>>>(pin_w, wb_pin, 1020, 192, 192);
  wcvt_kernel<<<(192 * 512 + 255) / 256, 256, 0, stream>>>(pout_w, wb_pout, 192, 510, 512);

  // ---- phase A ----
  ln_stats_kernel<<<2 * DIMC, 256, 0, stream>>>(x, ln1_w, ln1_b, sc1, sh1);
  ln_apply_t_kernel<<<dim3(64, 6, 2), 256, 0, stream>>>(x, sc1, sh1, Xt1);
  gemm_kernel<<<dim3(64, 9), 256, 0, stream>>>(wb_qkv, Xt1, qkv_b, nullptr, qkvbuf, nullptr, 576, 192, 0);
  dwconv_kernel<<<2 * 576, 256, 0, stream>>>(qkvbuf, qkv_dw_w, qkv_dw_b, qdw, 576);
  prep_v_kernel<<<dim3(192, 8), 256, 0, stream>>>(qdw, Vbf);
  prep_qk_kernel<<<128, 256, 0, stream>>>(qdw, temperature, Qbf, Kbf);
  attn_split_kernel<<<2048, 256, 0, stream>>>(Qbf, Kbf, Vbf, Opart);
  attn_merge_kernel<<<512, 256, 0, stream>>>(Opart, Xt_att);
  gemm_kernel<<<dim3(64, 3), 256, 0, stream>>>(wb_proj, Xt_att, proj_b, x, out, nullptr, 192, 192, 2);

  // ---- phase B ----
  ln_stats_kernel<<<2 * DIMC, 256, 0, stream>>>(out, ln2_w, ln2_b, sc2, sh2);
  ln_apply_t_kernel<<<dim3(64, 6, 2), 256, 0, stream>>>(out, sc2, sh2, Xt2);
  gemm_kernel<<<dim3(64, 16), 256, 0, stream>>>(wb_pin, Xt2, pin_b, nullptr, nullptr, hid, 1020, 192, 1);
  gdfn_dw_gate_kernel<<<2 * HIDC, 256, 0, stream>>>(hid, gdfn_dw_w, gdfn_dw_b, gate);
  transpose_gate_kernel<<<dim3(64, 16, 2), 256, 0, stream>>>(gate, Xt_gate);
  gemm_kernel<<<dim3(64, 3), 256, 0, stream>>>(wb_pout, Xt_gate, pout_b, out, out, nullptr, 192, 512, 2);
}

// Round 4
// 296.772 us; speedup vs baseline: 2.3831x; 1.0010x over previous
//
#include <hip/hip_runtime.h>
#include <hip/hip_bf16.h>

typedef __bf16 bf16x8 __attribute__((ext_vector_type(8)));
typedef __bf16 bf16x4 __attribute__((ext_vector_type(4)));
typedef __bf16 bf16x2 __attribute__((ext_vector_type(2)));
typedef float f32x4 __attribute__((ext_vector_type(4)));

#define HW 4096
#define DIMC 192
#define DH 48
#define HIDC 510

// ---------------- merged weight convert: all four fp32 [O][C] -> bf16 [O][Cp] ----------------
__global__ void wcvt4_kernel(const float* __restrict__ qkv_w, const float* __restrict__ proj_w,
                             const float* __restrict__ pin_w, const float* __restrict__ pout_w,
                             __bf16* __restrict__ wb_qkv, __bf16* __restrict__ wb_proj,
                             __bf16* __restrict__ wb_pin, __bf16* __restrict__ wb_pout) {
  int idx = blockIdx.x * 256 + threadIdx.x;
  if (idx < 110592) {                       // qkv 576x192
    wb_qkv[idx] = (__bf16)qkv_w[idx];
  } else if (idx < 147456) {                // proj 192x192
    int i = idx - 110592;
    wb_proj[i] = (__bf16)proj_w[i];
  } else if (idx < 343296) {                // pin 1020x192
    int i = idx - 147456;
    wb_pin[i] = (__bf16)pin_w[i];
  } else if (idx < 441600) {                // pout 192x512 (pad c 510,511)
    int i = idx - 343296;
    int o = i >> 9, c = i & 511;
    wb_pout[i] = (c < HIDC) ? (__bf16)pout_w[o * HIDC + c] : (__bf16)0.f;
  }
}

// ---------------- LN stats: per (b,c) -> sc = rstd*w, sh = b - mean*sc ----------------
__global__ __launch_bounds__(256) void ln_stats_kernel(const float* __restrict__ x, const float* __restrict__ w,
                                                       const float* __restrict__ b, float* __restrict__ sc,
                                                       float* __restrict__ sh) {
  int bc = blockIdx.x;            // b*DIMC + c
  int c = bc % DIMC;
  const float* row = x + (size_t)bc * HW;
  float s = 0.f, s2 = 0.f;
  for (int i = threadIdx.x; i < HW; i += 256) { float v = row[i]; s += v; s2 = fmaf(v, v, s2); }
  __shared__ float red[8];
  for (int off = 32; off; off >>= 1) { s += __shfl_down(s, off, 64); s2 += __shfl_down(s2, off, 64); }
  int wid = threadIdx.x >> 6;
  if ((threadIdx.x & 63) == 0) { red[wid] = s; red[4 + wid] = s2; }
  __syncthreads();
  if (threadIdx.x == 0) {
    s = red[0] + red[1] + red[2] + red[3];
    s2 = red[4] + red[5] + red[6] + red[7];
    float mean = s * (1.f / HW);
    float var = s2 * (1.f / HW) - mean * mean;
    float rstd = rsqrtf(var + 1e-6f);
    float scv = rstd * w[c];
    sc[bc] = scv;
    sh[bc] = b[c] - mean * scv;
  }
}

// ---------------- LN apply + transpose-convert: fp32 [b][192][n] -> bf16 Xt[(b*4096+n)][192] ----------------
__global__ __launch_bounds__(256) void ln_apply_t_kernel(const float* __restrict__ x, const float* __restrict__ sc,
                                                         const float* __restrict__ sh, __bf16* __restrict__ Xt) {
  int n0 = blockIdx.x * 64, c0 = blockIdx.y * 32, b = blockIdx.z;
  int t = threadIdx.x;
  int n = t & 63, cs = c0 + (t >> 6) * 8;
  __bf16 ob[8];
#pragma unroll
  for (int cc = 0; cc < 8; ++cc) {
    int c = cs + cc;
    float v = fmaf(x[((size_t)(b * DIMC + c)) * HW + n0 + n], sc[b * DIMC + c], sh[b * DIMC + c]);
    ob[cc] = (__bf16)v;
  }
  *(bf16x8*)&Xt[((size_t)((b << 12) + n0 + n)) * DIMC + cs] = *(bf16x8*)ob;
}

// ---------------- bf16 MFMA GEMM, K-step 64: out[b][o][n] = A[o][:]·Xt[b*4096+n][:] + bias ----------------
// mode 0: fp32 out; 1: bf16 out; 2: fp32 out + fp32 residual.
__global__ __launch_bounds__(256) void gemm_kernel(const __bf16* __restrict__ A, const __bf16* __restrict__ Bt,
                                                   const float* __restrict__ bias, const float* __restrict__ res,
                                                   float* __restrict__ outf, __bf16* __restrict__ outb,
                                                   int O, int Cs, int mode) {
  __shared__ __align__(16) __bf16 Asub[64 * 72];
  __shared__ __align__(16) __bf16 Bsub[128 * 72];
  const int t = threadIdx.x;
  const int lane = t & 63, wv = t >> 6;
  const int q4 = lane >> 4, l16 = lane & 15;
  int o0 = blockIdx.y * 64;
  if (o0 + 64 > O) o0 = O - 64;
  const int ntot0 = blockIdx.x * 128;
  const int b = ntot0 >> 12;

  f32x4 acc[8];
#pragma unroll
  for (int nt = 0; nt < 8; ++nt) acc[nt] = (f32x4){0.f, 0.f, 0.f, 0.f};

  for (int c0 = 0; c0 < Cs; c0 += 64) {
    __syncthreads();
#pragma unroll
    for (int j = 0; j < 2; ++j) {           // A: 64 rows x 64 c = 512 chunks
      int id = t + 256 * j;
      *(bf16x8*)&Asub[(id >> 3) * 72 + (id & 7) * 8] =
          *(const bf16x8*)&A[((size_t)(o0 + (id >> 3))) * Cs + c0 + (id & 7) * 8];
    }
#pragma unroll
    for (int j = 0; j < 4; ++j) {           // B: 128 rows x 64 c = 1024 chunks
      int id = t + 256 * j;
      *(bf16x8*)&Bsub[(id >> 3) * 72 + (id & 7) * 8] =
          *(const bf16x8*)&Bt[((size_t)(ntot0 + (id >> 3))) * Cs + c0 + (id & 7) * 8];
    }
    __syncthreads();
#pragma unroll
    for (int ks = 0; ks < 2; ++ks) {
      bf16x8 af = *(const bf16x8*)&Asub[(16 * wv + l16) * 72 + 32 * ks + 8 * q4];
#pragma unroll
      for (int nt = 0; nt < 8; ++nt) {
        bf16x8 bfr = *(const bf16x8*)&Bsub[(16 * nt + l16) * 72 + 32 * ks + 8 * q4];
        acc[nt] = __builtin_amdgcn_mfma_f32_16x16x32_bf16(af, bfr, acc[nt], 0, 0, 0);
      }
    }
  }

  float bvals[4];
#pragma unroll
  for (int r = 0; r < 4; ++r) bvals[r] = bias[o0 + 16 * wv + 4 * q4 + r];
#pragma unroll
  for (int nt = 0; nt < 8; ++nt) {
    int n_in_b = (ntot0 & 4095) + 16 * nt + l16;
#pragma unroll
    for (int r = 0; r < 4; ++r) {
      int o = o0 + 16 * wv + 4 * q4 + r;
      size_t addr = ((size_t)(b * O + o)) * HW + n_in_b;
      float v = acc[nt][r] + bvals[r];
      if (mode == 2) { outf[addr] = v + res[addr]; }
      else if (mode == 0) { outf[addr] = v; }
      else { outb[addr] = (__bf16)v; }
    }
  }
}

// ---------------- depthwise 3x3 on bf16 qkv; q,k -> qdwb bf16; v -> Vbf [bh][c][n] directly ----------------
__global__ __launch_bounds__(256) void dwconv_split_kernel(const __bf16* __restrict__ in, const float* __restrict__ w,
                                                           const float* __restrict__ bias,
                                                           __bf16* __restrict__ qdwb, __bf16* __restrict__ Vbf) {
  int bc = blockIdx.x;
  int b = bc / 576, ch = bc - b * 576;
  __shared__ float tile[66 * 68];
  for (int i = threadIdx.x; i < 66 * 68; i += 256) tile[i] = 0.f;
  __syncthreads();
  const __bf16* p = in + (size_t)bc * HW;
  for (int j = 0; j < 8; ++j) {
    int i = 2 * threadIdx.x + 512 * j;
    bf16x2 v = *(const bf16x2*)&p[i];
    int y = i >> 6, xx = i & 63;
    tile[(y + 1) * 68 + xx + 1] = (float)v.x;
    tile[(y + 1) * 68 + xx + 2] = (float)v.y;
  }
  __syncthreads();
  float w0 = w[ch * 9 + 0], w1 = w[ch * 9 + 1], w2 = w[ch * 9 + 2];
  float w3 = w[ch * 9 + 3], w4 = w[ch * 9 + 4], w5 = w[ch * 9 + 5];
  float w6 = w[ch * 9 + 6], w7 = w[ch * 9 + 7], w8 = w[ch * 9 + 8];
  float bb = bias[ch];
  __bf16* dst;
  if (ch < 384) dst = qdwb + ((size_t)(b * 384 + ch)) * HW;
  else {
    int c = ch - 384, h = c / DH, cc = c - h * DH;
    dst = Vbf + ((size_t)((b * 4 + h) * DH + cc)) * HW;
  }
  for (int j = 0; j < 8; ++j) {
    int i = 2 * threadIdx.x + 512 * j;
    int y = i >> 6, xx = i & 63;
    const float* tt = &tile[y * 68 + xx];
    float a = bb;
    a = fmaf(w0, tt[0], a);   a = fmaf(w1, tt[1], a);   a = fmaf(w2, tt[2], a);
    a = fmaf(w3, tt[68], a);  a = fmaf(w4, tt[69], a);  a = fmaf(w5, tt[70], a);
    a = fmaf(w6, tt[136], a); a = fmaf(w7, tt[137], a); a = fmaf(w8, tt[138], a);
    float a2 = bb;
    a2 = fmaf(w0, tt[1], a2);   a2 = fmaf(w1, tt[2], a2);   a2 = fmaf(w2, tt[3], a2);
    a2 = fmaf(w3, tt[69], a2);  a2 = fmaf(w4, tt[70], a2);  a2 = fmaf(w5, tt[71], a2);
    a2 = fmaf(w6, tt[137], a2); a2 = fmaf(w7, tt[138], a2); a2 = fmaf(w8, tt[139], a2);
    bf16x2 o = { (__bf16)a, (__bf16)a2 };
    *(bf16x2*)&dst[i] = o;
  }
}

// ---------------- GDFN: dw3x3 on bf16 hid ch j and j+510, gelu(a1)*a2 -> bf16 gate ----------------
__global__ __launch_bounds__(256) void gdfn_dw_gate_kernel(const __bf16* __restrict__ hid, const float* __restrict__ w,
                                                           const float* __restrict__ bias, __bf16* __restrict__ gate) {
  int blk = blockIdx.x;           // b*HIDC + j
  int b = blk / HIDC, j = blk - b * HIDC;
  __shared__ float t1[66 * 68];
  __shared__ float t2[66 * 68];
  for (int i = threadIdx.x; i < 66 * 68; i += 256) { t1[i] = 0.f; t2[i] = 0.f; }
  __syncthreads();
  const __bf16* p1 = hid + ((size_t)b * (2 * HIDC) + j) * HW;
  const __bf16* p2 = p1 + (size_t)HIDC * HW;
  for (int i = threadIdx.x; i < HW; i += 256) {
    int y = i >> 6, xx = i & 63;
    t1[(y + 1) * 68 + xx + 1] = (float)p1[i];
    t2[(y + 1) * 68 + xx + 1] = (float)p2[i];
  }
  __syncthreads();
  int c1 = j, c2 = j + HIDC;
  float a0 = w[c1*9+0], a1w = w[c1*9+1], a2w = w[c1*9+2], a3 = w[c1*9+3], a4 = w[c1*9+4],
        a5 = w[c1*9+5], a6 = w[c1*9+6], a7 = w[c1*9+7], a8 = w[c1*9+8];
  float b0 = w[c2*9+0], b1 = w[c2*9+1], b2 = w[c2*9+2], b3 = w[c2*9+3], b4 = w[c2*9+4],
        b5 = w[c2*9+5], b6 = w[c2*9+6], b7 = w[c2*9+7], b8 = w[c2*9+8];
  float bi1 = bias[c1], bi2 = bias[c2];
  __bf16* op = gate + ((size_t)b * HIDC + j) * HW;
  for (int i = threadIdx.x; i < HW; i += 256) {
    int y = i >> 6, xx = i & 63;
    const float* u = &t1[y * 68 + xx];
    const float* v = &t2[y * 68 + xx];
    float x1 = bi1;
    x1 = fmaf(a0, u[0], x1);   x1 = fmaf(a1w, u[1], x1);  x1 = fmaf(a2w, u[2], x1);
    x1 = fmaf(a3, u[68], x1);  x1 = fmaf(a4, u[69], x1);  x1 = fmaf(a5, u[70], x1);
    x1 = fmaf(a6, u[136], x1); x1 = fmaf(a7, u[137], x1); x1 = fmaf(a8, u[138], x1);
    float x2 = bi2;
    x2 = fmaf(b0, v[0], x2);   x2 = fmaf(b1, v[1], x2);   x2 = fmaf(b2, v[2], x2);
    x2 = fmaf(b3, v[68], x2);  x2 = fmaf(b4, v[69], x2);  x2 = fmaf(b5, v[70], x2);
    x2 = fmaf(b6, v[136], x2); x2 = fmaf(b7, v[137], x2); x2 = fmaf(b8, v[138], x2);
    float g = 0.5f * x1 * (1.f + erff(x1 * 0.70710678118654752f));
    op[i] = (__bf16)(g * x2);
  }
}

// ---------------- gate bf16 [b][510][n] -> Xt bf16 [(b*4096+n)][512] ----------------
__global__ __launch_bounds__(256) void transpose_gate_kernel(const __bf16* __restrict__ gate, __bf16* __restrict__ Xt) {
  int n0 = blockIdx.x * 64, c0 = blockIdx.y * 32, b = blockIdx.z;
  int t = threadIdx.x;
  int n = t & 63, cs = c0 + (t >> 6) * 8;
  __bf16 ob[8];
#pragma unroll
  for (int cc = 0; cc < 8; ++cc) {
    int c = cs + cc;
    ob[cc] = (c < HIDC) ? gate[((size_t)(b * HIDC + c)) * HW + n0 + n] : (__bf16)0.f;
  }
  *(bf16x8*)&Xt[((size_t)((b << 12) + n0 + n)) * 512 + cs] = *(bf16x8*)ob;
}

// ---------------- prep: normalize q,k from bf16 qdwb, fold temperature into q, emit [bh][n][64] ----------------
__global__ __launch_bounds__(256) void prep_qk_kernel(const __bf16* __restrict__ qdwb, const float* __restrict__ temp,
                                                      __bf16* __restrict__ Qbf, __bf16* __restrict__ Kbf) {
  int gid = blockIdx.x * 256 + threadIdx.x;   // bh*4096 + n
  int bh = gid >> 12, n = gid & 4095;
  int b = bh >> 2, h = bh & 3;
  const __bf16* qp = qdwb + ((size_t)(b * 384 + h * DH)) * HW + n;
  const __bf16* kp = qp + (size_t)192 * HW;
  float buf[DH];
  float ss = 0.f;
#pragma unroll
  for (int c = 0; c < DH; ++c) { buf[c] = (float)qp[(size_t)c * HW]; ss = fmaf(buf[c], buf[c], ss); }
  float sc = temp[h] / fmaxf(sqrtf(ss), 1e-12f);
  __bf16 ob[64];
#pragma unroll
  for (int c = 0; c < DH; ++c) ob[c] = (__bf16)(buf[c] * sc);
#pragma unroll
  for (int c = DH; c < 64; ++c) ob[c] = (__bf16)0.f;
  __bf16* qd = Qbf + (size_t)gid * 64;
#pragma unroll
  for (int ch = 0; ch < 8; ++ch) *(bf16x8*)&qd[ch * 8] = *(bf16x8*)&ob[ch * 8];

  ss = 0.f;
#pragma unroll
  for (int c = 0; c < DH; ++c) { buf[c] = (float)kp[(size_t)c * HW]; ss = fmaf(buf[c], buf[c], ss); }
  sc = 1.f / fmaxf(sqrtf(ss), 1e-12f);
#pragma unroll
  for (int c = 0; c < DH; ++c) ob[c] = (__bf16)(buf[c] * sc);
  __bf16* kd = Kbf + (size_t)gid * 64;
#pragma unroll
  for (int ch = 0; ch < 8; ++ch) *(bf16x8*)&kd[ch * 8] = *(bf16x8*)&ob[ch * 8];
}

// ---------------- flash attention split-K, 128n x 64m tiles, S^T trick for packed P writes ----------------
// grid 1024 = chunk*256 + bh*32 + nt; block 256 (4 waves).
// Partial per block: O[128 n][48 c] fp32 + l[128] at part[bid*6272].
__global__ __launch_bounds__(256) void attn_split_kernel(const __bf16* __restrict__ Qbf, const __bf16* __restrict__ Kbf,
                                                         const __bf16* __restrict__ Vbf, float* __restrict__ part) {
  __shared__ __align__(16) __bf16 Qt[128 * 72];  // Qt[n][c]
  __shared__ __align__(16) __bf16 Kt[64 * 72];   // Kt[m][c]  (reused as float Lred[4][128] in epilogue)
  __shared__ __align__(16) __bf16 Vc[48 * 72];   // Vc[c][m]
  __shared__ __align__(16) __bf16 Pl[128 * 72];  // Pl[n][m]
  const int tid = threadIdx.x;
  const int lane = tid & 63;
  const int wv = tid >> 6;
  const int q4 = lane >> 4, l16 = lane & 15;
  const int bid = blockIdx.x;
  const int chunk = bid >> 8, rest = bid & 255;
  const int bh = rest >> 5, nt = rest & 31;
  const int n0 = nt * 128;
  const __bf16* Qg = Qbf + (size_t)bh * HW * 64;
  const __bf16* Kg = Kbf + (size_t)bh * HW * 64;
  const __bf16* Vg = Vbf + (size_t)bh * DH * HW;

  // stage Q tile: 128 rows x 64 c
#pragma unroll
  for (int j = 0; j < 4; ++j) {
    int id = tid + 256 * j;
    *(bf16x8*)&Qt[(id >> 3) * 72 + (id & 7) * 8] = *(const bf16x8*)&Qg[((size_t)(n0 + (id >> 3))) * 64 + (id & 7) * 8];
  }

  float lsub[8];
#pragma unroll
  for (int s = 0; s < 8; ++s) lsub[s] = 0.f;
  f32x4 oacc[2][3];
#pragma unroll
  for (int st = 0; st < 2; ++st)
#pragma unroll
    for (int ct = 0; ct < 3; ++ct) oacc[st][ct] = (f32x4){0.f, 0.f, 0.f, 0.f};

  for (int mt = chunk * 16; mt < chunk * 16 + 16; ++mt) {
    const int m0 = mt * 64;
    __syncthreads();                     // prior PV reads of Kt/Vc/Pl complete
#pragma unroll
    for (int j = 0; j < 2; ++j) {        // Kt: 64 x 64
      int id = tid + 256 * j;
      *(bf16x8*)&Kt[(id >> 3) * 72 + (id & 7) * 8] = *(const bf16x8*)&Kg[((size_t)(m0 + (id >> 3))) * 64 + (id & 7) * 8];
    }
    for (int i = tid; i < 384; i += 256) // Vc: 48 x 64
      *(bf16x8*)&Vc[(i >> 3) * 72 + (i & 7) * 8] = *(const bf16x8*)&Vg[((size_t)(i >> 3)) * HW + m0 + (i & 7) * 8];
    __syncthreads();

    // S^T[m][n] = K·Q^T: wave owns m-strip 16wv; computes all 128 n (8 s-tiles)
    f32x4 sacc[8];
#pragma unroll
    for (int s = 0; s < 8; ++s) sacc[s] = (f32x4){0.f, 0.f, 0.f, 0.f};
#pragma unroll
    for (int ks = 0; ks < 2; ++ks) {
      bf16x8 af = *(const bf16x8*)&Kt[(16 * wv + l16) * 72 + 32 * ks + 8 * q4];
#pragma unroll
      for (int s = 0; s < 8; ++s) {
        bf16x8 bq = *(const bf16x8*)&Qt[(16 * s + l16) * 72 + 32 * ks + 8 * q4];
        sacc[s] = __builtin_amdgcn_mfma_f32_16x16x32_bf16(af, bq, sacc[s], 0, 0, 0);
      }
    }

    // maxless softmax; C rows = m (16wv+4q4+r), col = n (16s+l16); packed b64 P writes (m-contig)
#pragma unroll
    for (int s = 0; s < 8; ++s) {
      float p0 = __expf(sacc[s][0]);
      float p1 = __expf(sacc[s][1]);
      float p2 = __expf(sacc[s][2]);
      float p3 = __expf(sacc[s][3]);
      lsub[s] += (p0 + p1) + (p2 + p3);
      bf16x4 pk = { (__bf16)p0, (__bf16)p1, (__bf16)p2, (__bf16)p3 };
      *(bf16x4*)&Pl[(16 * s + l16) * 72 + 16 * wv + 4 * q4] = pk;
    }
    __syncthreads();                     // Pl visible to all waves

    // O[n][c] += P·V^T: wave owns n-strips 32wv + {0,16}
#pragma unroll
    for (int ks = 0; ks < 2; ++ks) {
      bf16x8 pf0 = *(const bf16x8*)&Pl[(32 * wv + l16) * 72 + 32 * ks + 8 * q4];
      bf16x8 pf1 = *(const bf16x8*)&Pl[(32 * wv + 16 + l16) * 72 + 32 * ks + 8 * q4];
#pragma unroll
      for (int ct = 0; ct < 3; ++ct) {
        bf16x8 vf = *(const bf16x8*)&Vc[(16 * ct + l16) * 72 + 32 * ks + 8 * q4];
        oacc[0][ct] = __builtin_amdgcn_mfma_f32_16x16x32_bf16(pf0, vf, oacc[0][ct], 0, 0, 0);
        oacc[1][ct] = __builtin_amdgcn_mfma_f32_16x16x32_bf16(pf1, vf, oacc[1][ct], 0, 0, 0);
      }
    }
  }

  // epilogue: reduce lsub over q4 lanes, then over waves via LDS (reuse Kt)
  __syncthreads();
  float* Lred = (float*)Kt;
#pragma unroll
  for (int s = 0; s < 8; ++s) {
    float v = lsub[s];
    v += __shfl_xor(v, 16, 64);
    v += __shfl_xor(v, 32, 64);
    if (q4 == 0) Lred[wv * 128 + 16 * s + l16] = v;
  }
  __syncthreads();
  size_t pbase = (size_t)bid * 6272;
  if (tid < 128)
    part[pbase + 6144 + tid] = Lred[tid] + Lred[128 + tid] + Lred[256 + tid] + Lred[384 + tid];
#pragma unroll
  for (int st = 0; st < 2; ++st)
#pragma unroll
    for (int ct = 0; ct < 3; ++ct)
#pragma unroll
      for (int r = 0; r < 4; ++r) {
        int n = 32 * wv + 16 * st + 4 * q4 + r;
        part[pbase + (size_t)n * 48 + 16 * ct + l16] = oacc[st][ct][r];
      }
}

// ---------------- merge 4 chunks + normalize -> Xt_att bf16 [(b*4096+n)][192] ----------------
// grid 256 = bh*32 + nt(128)
__global__ __launch_bounds__(256) void attn_merge_kernel(const float* __restrict__ part, __bf16* __restrict__ Xt) {
  const int bid = blockIdx.x;
  const int bh = bid >> 5, nt = bid & 31;
  const int b = bh >> 2, h = bh & 3;
  const int n0 = nt * 128;
  const int t = threadIdx.x;
  __shared__ float linv[128];
  if (t < 128) {
    float s = 0.f;
#pragma unroll
    for (int ch = 0; ch < 4; ++ch) s += part[((size_t)(ch * 256 + bid)) * 6272 + 6144 + t];
    linv[t] = 1.f / s;
  }
  __syncthreads();
#pragma unroll
  for (int j = 0; j < 6; ++j) {
    int id = t + 256 * j;          // 1536 f32x4 chunks: n = id/12, c4 = (id%12)*4
    int n = id / 12, cc = (id - n * 12) * 4;
    f32x4 s = (f32x4){0.f, 0.f, 0.f, 0.f};
#pragma unroll
    for (int ch = 0; ch < 4; ++ch) s += *(const f32x4*)&part[((size_t)(ch * 256 + bid)) * 6272 + (size_t)n * 48 + cc];
    float li = linv[n];
    bf16x4 ov = { (__bf16)(s.x * li), (__bf16)(s.y * li), (__bf16)(s.z * li), (__bf16)(s.w * li) };
    *(bf16x4*)&Xt[((size_t)((b << 12) + n0 + n)) * DIMC + h * DH + cc] = ov;
  }
}

extern "C" void kernel_launch(void* const* d_in, const int* in_sizes, int n_in,
                              void* d_out, int out_size, void* d_ws, size_t ws_size,
                              hipStream_t stream) {
  const float* x        = (const float*)d_in[0];
  const float* ln1_w    = (const float*)d_in[1];
  const float* ln1_b    = (const float*)d_in[2];
  const float* qkv_w    = (const float*)d_in[3];
  const float* qkv_b    = (const float*)d_in[4];
  const float* qkv_dw_w = (const float*)d_in[5];
  const float* qkv_dw_b = (const float*)d_in[6];
  const float* temperature = (const float*)d_in[7];
  const float* proj_w   = (const float*)d_in[8];
  const float* proj_b   = (const float*)d_in[9];
  const float* ln2_w    = (const float*)d_in[10];
  const float* ln2_b    = (const float*)d_in[11];
  const float* pin_w    = (const float*)d_in[12];
  const float* pin_b    = (const float*)d_in[13];
  const float* gdfn_dw_w = (const float*)d_in[14];
  const float* gdfn_dw_b = (const float*)d_in[15];
  const float* pout_w   = (const float*)d_in[16];
  const float* pout_b   = (const float*)d_in[17];
  float* out = (float*)d_out;
  float* ws = (float*)d_ws;

  // ---- workspace layout (float offsets) ----
  __bf16* wb_qkv  = (__bf16*)(ws + 0);          // 55296 f
  __bf16* wb_proj = (__bf16*)(ws + 55296);      // 18432 f
  __bf16* wb_pin  = (__bf16*)(ws + 73728);      // 97920 f
  __bf16* wb_pout = (__bf16*)(ws + 171648);     // 49152 f
  float* sc1 = ws + 220800;
  float* sh1 = ws + 221184;
  float* sc2 = ws + 221568;
  float* sh2 = ws + 221952;                     // ends 222336
  // region B @222336 (2,883,584 f): Xt1 / Xt2 overlap Qbf; Q/K/V bf16
  __bf16* Xt1 = (__bf16*)(ws + 222336);         // 786,432 f (dead after gemm_qkv)
  __bf16* Xt2 = (__bf16*)(ws + 222336);         // phase B reuse
  __bf16* Qbf = (__bf16*)(ws + 222336);         // 1,048,576 f
  __bf16* Kbf = (__bf16*)(ws + 1270912);        // 1,048,576 f
  __bf16* Vbf = (__bf16*)(ws + 2319488);        // 786,432 f -> ends 3,105,920
  // region C @3,105,920: qkvb bf16 (2,359,296 f) -> later Xt_att (786,432 f) -> later hid (4,177,920 f)
  __bf16* qkvb   = (__bf16*)(ws + 3105920);
  __bf16* Xt_att = (__bf16*)(ws + 3105920);
  __bf16* hid    = (__bf16*)(ws + 3105920);     // ends 7,283,840 (overlaps dead Opart tail)
  // region D @5,465,216 (6,422,528 f): qdwb (1,572,864 f, dead before attn) then Opart
  __bf16* qdwb  = (__bf16*)(ws + 5465216);
  float*  Opart = ws + 5465216;                 // 1024*6272 = 6,422,528 f -> ends 11,887,744
  __bf16* gate    = (__bf16*)(ws + 7283840);    // 2,088,960 f (phase B, Opart dead)
  __bf16* Xt_gate = (__bf16*)(ws + 9372800);    // 2,097,152 f -> ends 11,469,952
  // total 11,887,744 f = 47.6 MB

  wcvt4_kernel<<<1725, 256, 0, stream>>>(qkv_w, proj_w, pin_w, pout_w, wb_qkv, wb_proj, wb_pin, wb_pout);

  // ---- phase A ----
  ln_stats_kernel<<<2 * DIMC, 256, 0, stream>>>(x, ln1_w, ln1_b, sc1, sh1);
  ln_apply_t_kernel<<<dim3(64, 6, 2), 256, 0, stream>>>(x, sc1, sh1, Xt1);
  gemm_kernel<<<dim3(64, 9), 256, 0, stream>>>(wb_qkv, Xt1, qkv_b, nullptr, nullptr, qkvb, 576, 192, 1);
  dwconv_split_kernel<<<1152, 256, 0, stream>>>(qkvb, qkv_dw_w, qkv_dw_b, qdwb, Vbf);
  prep_qk_kernel<<<128, 256, 0, stream>>>(qdwb, temperature, Qbf, Kbf);
  attn_split_kernel<<<1024, 256, 0, stream>>>(Qbf, Kbf, Vbf, Opart);
  attn_merge_kernel<<<256, 256, 0, stream>>>(Opart, Xt_att);
  gemm_kernel<<<dim3(64, 3), 256, 0, stream>>>(wb_proj, Xt_att, proj_b, x, out, nullptr, 192, 192, 2);

  // ---- phase B ----
  ln_stats_kernel<<<2 * DIMC, 256, 0, stream>>>(out, ln2_w, ln2_b, sc2, sh2);
  ln_apply_t_kernel<<<dim3(64, 6, 2), 256, 0, stream>>>(out, sc2, sh2, Xt2);
  gemm_kernel<<<dim3(64, 16), 256, 0, stream>>>(wb_pin, Xt2, pin_b, nullptr, nullptr, hid, 1020, 192, 1);
  gdfn_dw_gate_kernel<<<2 * HIDC, 256, 0, stream>>>(hid, gdfn_dw_w, gdfn_dw_b, gate);
  transpose_gate_kernel<<<dim3(64, 16, 2), 256, 0, stream>>>(gate, Xt_gate);
  gemm_kernel<<<dim3(64, 3), 256, 0, stream>>>(wb_pout, Xt_gate, pout_b, out, out, nullptr, 192, 512, 2);
}

// Round 6
// 268.924 us; speedup vs baseline: 2.6299x; 1.1036x over previous
//
#include <hip/hip_runtime.h>
#include <hip/hip_bf16.h>

typedef __bf16 bf16x8 __attribute__((ext_vector_type(8)));
typedef __bf16 bf16x4 __attribute__((ext_vector_type(4)));
typedef __bf16 bf16x2 __attribute__((ext_vector_type(2)));
typedef float f32x4 __attribute__((ext_vector_type(4)));

#define HW 4096
#define DIMC 192
#define DH 48
#define HIDC 510

// ---------------- merged weight convert: all four fp32 [O][C] -> bf16 [O][Cp] ----------------
__global__ void wcvt4_kernel(const float* __restrict__ qkv_w, const float* __restrict__ proj_w,
                             const float* __restrict__ pin_w, const float* __restrict__ pout_w,
                             __bf16* __restrict__ wb_qkv, __bf16* __restrict__ wb_proj,
                             __bf16* __restrict__ wb_pin, __bf16* __restrict__ wb_pout) {
  int idx = blockIdx.x * 256 + threadIdx.x;
  if (idx < 110592) {                       // qkv 576x192
    wb_qkv[idx] = (__bf16)qkv_w[idx];
  } else if (idx < 147456) {                // proj 192x192
    int i = idx - 110592;
    wb_proj[i] = (__bf16)proj_w[i];
  } else if (idx < 343296) {                // pin 1020x192
    int i = idx - 147456;
    wb_pin[i] = (__bf16)pin_w[i];
  } else if (idx < 441600) {                // pout 192x512 (pad c 510,511)
    int i = idx - 343296;
    int o = i >> 9, c = i & 511;
    wb_pout[i] = (c < HIDC) ? (__bf16)pout_w[o * HIDC + c] : (__bf16)0.f;
  }
}

// ---------------- LN stats: per (b,c) -> sc = rstd*w, sh = b - mean*sc ----------------
__global__ __launch_bounds__(256) void ln_stats_kernel(const float* __restrict__ x, const float* __restrict__ w,
                                                       const float* __restrict__ b, float* __restrict__ sc,
                                                       float* __restrict__ sh) {
  int bc = blockIdx.x;            // b*DIMC + c
  int c = bc % DIMC;
  const float* row = x + (size_t)bc * HW;
  float s = 0.f, s2 = 0.f;
  for (int i = threadIdx.x; i < HW; i += 256) { float v = row[i]; s += v; s2 = fmaf(v, v, s2); }
  __shared__ float red[8];
  for (int off = 32; off; off >>= 1) { s += __shfl_down(s, off, 64); s2 += __shfl_down(s2, off, 64); }
  int wid = threadIdx.x >> 6;
  if ((threadIdx.x & 63) == 0) { red[wid] = s; red[4 + wid] = s2; }
  __syncthreads();
  if (threadIdx.x == 0) {
    s = red[0] + red[1] + red[2] + red[3];
    s2 = red[4] + red[5] + red[6] + red[7];
    float mean = s * (1.f / HW);
    float var = s2 * (1.f / HW) - mean * mean;
    float rstd = rsqrtf(var + 1e-6f);
    float scv = rstd * w[c];
    sc[bc] = scv;
    sh[bc] = b[c] - mean * scv;
  }
}

// ---------------- LN apply + transpose-convert: fp32 [b][192][n] -> bf16 Xt[(b*4096+n)][192] ----------------
__global__ __launch_bounds__(256) void ln_apply_t_kernel(const float* __restrict__ x, const float* __restrict__ sc,
                                                         const float* __restrict__ sh, __bf16* __restrict__ Xt) {
  int n0 = blockIdx.x * 64, c0 = blockIdx.y * 32, b = blockIdx.z;
  int t = threadIdx.x;
  int n = t & 63, cs = c0 + (t >> 6) * 8;
  __bf16 ob[8];
#pragma unroll
  for (int cc = 0; cc < 8; ++cc) {
    int c = cs + cc;
    float v = fmaf(x[((size_t)(b * DIMC + c)) * HW + n0 + n], sc[b * DIMC + c], sh[b * DIMC + c]);
    ob[cc] = (__bf16)v;
  }
  *(bf16x8*)&Xt[((size_t)((b << 12) + n0 + n)) * DIMC + cs] = *(bf16x8*)ob;
}

// ---------------- bf16 MFMA GEMM, K-step 64 ----------------
// mode 0: fp32 out; 1: bf16 out; 2: fp32 out + fp32 residual;
// mode 3: like 2 but B is bf16 [b][510][n] (gate) transposed+padded on the fly (Cs must be 512).
__global__ __launch_bounds__(256) void gemm_kernel(const __bf16* __restrict__ A, const __bf16* __restrict__ Bt,
                                                   const float* __restrict__ bias, const float* __restrict__ res,
                                                   float* __restrict__ outf, __bf16* __restrict__ outb,
                                                   int O, int Cs, int mode) {
  __shared__ __align__(16) __bf16 Asub[64 * 72];
  __shared__ __align__(16) __bf16 Bsub[128 * 72];
  const int t = threadIdx.x;
  const int lane = t & 63, wv = t >> 6;
  const int q4 = lane >> 4, l16 = lane & 15;
  int o0 = blockIdx.y * 64;
  if (o0 + 64 > O) o0 = O - 64;
  const int ntot0 = blockIdx.x * 128;
  const int b = ntot0 >> 12;
  const int n_in_b0 = ntot0 & 4095;

  f32x4 acc[8];
#pragma unroll
  for (int nt = 0; nt < 8; ++nt) acc[nt] = (f32x4){0.f, 0.f, 0.f, 0.f};

  for (int c0 = 0; c0 < Cs; c0 += 64) {
    __syncthreads();
#pragma unroll
    for (int j = 0; j < 2; ++j) {           // A: 64 rows x 64 c
      int id = t + 256 * j;
      *(bf16x8*)&Asub[(id >> 3) * 72 + (id & 7) * 8] =
          *(const bf16x8*)&A[((size_t)(o0 + (id >> 3))) * Cs + c0 + (id & 7) * 8];
    }
    if (mode != 3) {
#pragma unroll
      for (int j = 0; j < 4; ++j) {         // B: 128 rows x 64 c from [n][c] layout
        int id = t + 256 * j;
        *(bf16x8*)&Bsub[(id >> 3) * 72 + (id & 7) * 8] =
            *(const bf16x8*)&Bt[((size_t)(ntot0 + (id >> 3))) * Cs + c0 + (id & 7) * 8];
      }
    } else {
      // transposing stage from gate [b][510][n]: thread t covers c-row (t>>2), 32-n segment (t&3)
      int cr = t >> 2, seg = t & 3;
      int cg = c0 + cr;
      __bf16 tmp[32];
      if (cg < HIDC) {
        const __bf16* gp = Bt + ((size_t)(b * HIDC + cg)) * HW + n_in_b0 + seg * 32;
#pragma unroll
        for (int j = 0; j < 4; ++j) *(bf16x8*)&tmp[8 * j] = *(const bf16x8*)&gp[8 * j];
      } else {
#pragma unroll
        for (int k = 0; k < 32; ++k) tmp[k] = (__bf16)0.f;
      }
#pragma unroll
      for (int k = 0; k < 32; ++k) Bsub[(seg * 32 + k) * 72 + cr] = tmp[k];
    }
    __syncthreads();
#pragma unroll
    for (int ks = 0; ks < 2; ++ks) {
      bf16x8 af = *(const bf16x8*)&Asub[(16 * wv + l16) * 72 + 32 * ks + 8 * q4];
#pragma unroll
      for (int nt = 0; nt < 8; ++nt) {
        bf16x8 bfr = *(const bf16x8*)&Bsub[(16 * nt + l16) * 72 + 32 * ks + 8 * q4];
        acc[nt] = __builtin_amdgcn_mfma_f32_16x16x32_bf16(af, bfr, acc[nt], 0, 0, 0);
      }
    }
  }

  float bvals[4];
#pragma unroll
  for (int r = 0; r < 4; ++r) bvals[r] = bias[o0 + 16 * wv + 4 * q4 + r];
#pragma unroll
  for (int nt = 0; nt < 8; ++nt) {
    int n_in_b = n_in_b0 + 16 * nt + l16;
#pragma unroll
    for (int r = 0; r < 4; ++r) {
      int o = o0 + 16 * wv + 4 * q4 + r;
      size_t addr = ((size_t)(b * O + o)) * HW + n_in_b;
      float v = acc[nt][r] + bvals[r];
      if (mode >= 2) { outf[addr] = v + res[addr]; }
      else if (mode == 0) { outf[addr] = v; }
      else { outb[addr] = (__bf16)v; }
    }
  }
}

// ---------------- depthwise 3x3 on bf16 qkv; q,k -> qdwb bf16; v -> Vbf [bh][c][n] directly ----------------
__global__ __launch_bounds__(256) void dwconv_split_kernel(const __bf16* __restrict__ in, const float* __restrict__ w,
                                                           const float* __restrict__ bias,
                                                           __bf16* __restrict__ qdwb, __bf16* __restrict__ Vbf) {
  int bc = blockIdx.x;
  int b = bc / 576, ch = bc - b * 576;
  __shared__ float tile[66 * 68];
  for (int i = threadIdx.x; i < 66 * 68; i += 256) tile[i] = 0.f;
  __syncthreads();
  const __bf16* p = in + (size_t)bc * HW;
  for (int j = 0; j < 8; ++j) {
    int i = 2 * threadIdx.x + 512 * j;
    bf16x2 v = *(const bf16x2*)&p[i];
    int y = i >> 6, xx = i & 63;
    tile[(y + 1) * 68 + xx + 1] = (float)v.x;
    tile[(y + 1) * 68 + xx + 2] = (float)v.y;
  }
  __syncthreads();
  float w0 = w[ch * 9 + 0], w1 = w[ch * 9 + 1], w2 = w[ch * 9 + 2];
  float w3 = w[ch * 9 + 3], w4 = w[ch * 9 + 4], w5 = w[ch * 9 + 5];
  float w6 = w[ch * 9 + 6], w7 = w[ch * 9 + 7], w8 = w[ch * 9 + 8];
  float bb = bias[ch];
  __bf16* dst;
  if (ch < 384) dst = qdwb + ((size_t)(b * 384 + ch)) * HW;
  else {
    int c = ch - 384, h = c / DH, cc = c - h * DH;
    dst = Vbf + ((size_t)((b * 4 + h) * DH + cc)) * HW;
  }
  for (int j = 0; j < 8; ++j) {
    int i = 2 * threadIdx.x + 512 * j;
    int y = i >> 6, xx = i & 63;
    const float* tt = &tile[y * 68 + xx];
    float a = bb;
    a = fmaf(w0, tt[0], a);   a = fmaf(w1, tt[1], a);   a = fmaf(w2, tt[2], a);
    a = fmaf(w3, tt[68], a);  a = fmaf(w4, tt[69], a);  a = fmaf(w5, tt[70], a);
    a = fmaf(w6, tt[136], a); a = fmaf(w7, tt[137], a); a = fmaf(w8, tt[138], a);
    float a2 = bb;
    a2 = fmaf(w0, tt[1], a2);   a2 = fmaf(w1, tt[2], a2);   a2 = fmaf(w2, tt[3], a2);
    a2 = fmaf(w3, tt[69], a2);  a2 = fmaf(w4, tt[70], a2);  a2 = fmaf(w5, tt[71], a2);
    a2 = fmaf(w6, tt[137], a2); a2 = fmaf(w7, tt[138], a2); a2 = fmaf(w8, tt[139], a2);
    bf16x2 o = { (__bf16)a, (__bf16)a2 };
    *(bf16x2*)&dst[i] = o;
  }
}

// ---------------- GDFN: dw3x3 on bf16 hid ch j and j+510, gelu(a1)*a2 -> bf16 gate ----------------
__global__ __launch_bounds__(256) void gdfn_dw_gate_kernel(const __bf16* __restrict__ hid, const float* __restrict__ w,
                                                           const float* __restrict__ bias, __bf16* __restrict__ gate) {
  int blk = blockIdx.x;           // b*HIDC + j
  int b = blk / HIDC, j = blk - b * HIDC;
  __shared__ float t1[66 * 68];
  __shared__ float t2[66 * 68];
  for (int i = threadIdx.x; i < 66 * 68; i += 256) { t1[i] = 0.f; t2[i] = 0.f; }
  __syncthreads();
  const __bf16* p1 = hid + ((size_t)b * (2 * HIDC) + j) * HW;
  const __bf16* p2 = p1 + (size_t)HIDC * HW;
  for (int i = threadIdx.x; i < HW; i += 256) {
    int y = i >> 6, xx = i & 63;
    t1[(y + 1) * 68 + xx + 1] = (float)p1[i];
    t2[(y + 1) * 68 + xx + 1] = (float)p2[i];
  }
  __syncthreads();
  int c1 = j, c2 = j + HIDC;
  float a0 = w[c1*9+0], a1w = w[c1*9+1], a2w = w[c1*9+2], a3 = w[c1*9+3], a4 = w[c1*9+4],
        a5 = w[c1*9+5], a6 = w[c1*9+6], a7 = w[c1*9+7], a8 = w[c1*9+8];
  float b0 = w[c2*9+0], b1 = w[c2*9+1], b2 = w[c2*9+2], b3 = w[c2*9+3], b4 = w[c2*9+4],
        b5 = w[c2*9+5], b6 = w[c2*9+6], b7 = w[c2*9+7], b8 = w[c2*9+8];
  float bi1 = bias[c1], bi2 = bias[c2];
  __bf16* op = gate + ((size_t)b * HIDC + j) * HW;
  for (int i = threadIdx.x; i < HW; i += 256) {
    int y = i >> 6, xx = i & 63;
    const float* u = &t1[y * 68 + xx];
    const float* v = &t2[y * 68 + xx];
    float x1 = bi1;
    x1 = fmaf(a0, u[0], x1);   x1 = fmaf(a1w, u[1], x1);  x1 = fmaf(a2w, u[2], x1);
    x1 = fmaf(a3, u[68], x1);  x1 = fmaf(a4, u[69], x1);  x1 = fmaf(a5, u[70], x1);
    x1 = fmaf(a6, u[136], x1); x1 = fmaf(a7, u[137], x1); x1 = fmaf(a8, u[138], x1);
    float x2 = bi2;
    x2 = fmaf(b0, v[0], x2);   x2 = fmaf(b1, v[1], x2);   x2 = fmaf(b2, v[2], x2);
    x2 = fmaf(b3, v[68], x2);  x2 = fmaf(b4, v[69], x2);  x2 = fmaf(b5, v[70], x2);
    x2 = fmaf(b6, v[136], x2); x2 = fmaf(b7, v[137], x2); x2 = fmaf(b8, v[138], x2);
    float g = 0.5f * x1 * (1.f + erff(x1 * 0.70710678118654752f));
    op[i] = (__bf16)(g * x2);
  }
}

// ---------------- prep: normalize q,k from bf16 qdwb, fold temperature into q, emit [bh][n][64] ----------------
__global__ __launch_bounds__(256) void prep_qk_kernel(const __bf16* __restrict__ qdwb, const float* __restrict__ temp,
                                                      __bf16* __restrict__ Qbf, __bf16* __restrict__ Kbf) {
  int gid = blockIdx.x * 256 + threadIdx.x;   // bh*4096 + n
  int bh = gid >> 12, n = gid & 4095;
  int b = bh >> 2, h = bh & 3;
  const __bf16* qp = qdwb + ((size_t)(b * 384 + h * DH)) * HW + n;
  const __bf16* kp = qp + (size_t)192 * HW;
  float buf[DH];
  float ss = 0.f;
#pragma unroll
  for (int c = 0; c < DH; ++c) { buf[c] = (float)qp[(size_t)c * HW]; ss = fmaf(buf[c], buf[c], ss); }
  float sc = temp[h] / fmaxf(sqrtf(ss), 1e-12f);
  __bf16 ob[64];
#pragma unroll
  for (int c = 0; c < DH; ++c) ob[c] = (__bf16)(buf[c] * sc);
#pragma unroll
  for (int c = DH; c < 64; ++c) ob[c] = (__bf16)0.f;
  __bf16* qd = Qbf + (size_t)gid * 64;
#pragma unroll
  for (int ch = 0; ch < 8; ++ch) *(bf16x8*)&qd[ch * 8] = *(bf16x8*)&ob[ch * 8];

  ss = 0.f;
#pragma unroll
  for (int c = 0; c < DH; ++c) { buf[c] = (float)kp[(size_t)c * HW]; ss = fmaf(buf[c], buf[c], ss); }
  sc = 1.f / fmaxf(sqrtf(ss), 1e-12f);
#pragma unroll
  for (int c = 0; c < DH; ++c) ob[c] = (__bf16)(buf[c] * sc);
  __bf16* kd = Kbf + (size_t)gid * 64;
#pragma unroll
  for (int ch = 0; ch < 8; ++ch) *(bf16x8*)&kd[ch * 8] = *(bf16x8*)&ob[ch * 8];
}

// ---------------- flash attention split-K: 64n x 64m tiles, Q in registers, S^T packed-P ----------------
// grid 2048 = chunk*512 + bh*64 + nt; block 256 (4 waves).
// Partial per block: O[64 n][48 c] fp32 + l[64] at part[bid*3136].
__global__ __launch_bounds__(256) void attn_split_kernel(const __bf16* __restrict__ Qbf, const __bf16* __restrict__ Kbf,
                                                         const __bf16* __restrict__ Vbf, float* __restrict__ part) {
  __shared__ __align__(16) __bf16 Kt[64 * 72];   // Kt[m][c]  (reused as float Lred[4][64] in epilogue)
  __shared__ __align__(16) __bf16 Vc[48 * 72];   // Vc[c][m]
  __shared__ __align__(16) __bf16 Pl[64 * 72];   // Pl[n][m]
  const int tid = threadIdx.x;
  const int lane = tid & 63;
  const int wv = tid >> 6;
  const int q4 = lane >> 4, l16 = lane & 15;
  const int bid = blockIdx.x;
  const int chunk = bid >> 9, rest = bid & 511;
  const int bh = rest >> 6, nt = rest & 63;
  const int n0 = nt * 64;
  const __bf16* Qg = Qbf + (size_t)bh * HW * 64;
  const __bf16* Kg = Kbf + (size_t)bh * HW * 64;
  const __bf16* Vg = Vbf + (size_t)bh * DH * HW;

  // Q fragments in registers: B-operand for S^T, shared by all waves.
  // qf[s][ks] = Q[n = n0+16s+l16][c = 32ks+8q4 .. +7]
  bf16x8 qf[4][2];
#pragma unroll
  for (int s = 0; s < 4; ++s)
#pragma unroll
    for (int ks = 0; ks < 2; ++ks)
      qf[s][ks] = *(const bf16x8*)&Qg[((size_t)(n0 + 16 * s + l16)) * 64 + 32 * ks + 8 * q4];

  float lsub[4] = {0.f, 0.f, 0.f, 0.f};
  f32x4 oacc[3];
#pragma unroll
  for (int ct = 0; ct < 3; ++ct) oacc[ct] = (f32x4){0.f, 0.f, 0.f, 0.f};

  for (int mt = chunk * 16; mt < chunk * 16 + 16; ++mt) {
    const int m0 = mt * 64;
    __syncthreads();                     // prior S reads of Kt + PV reads of Vc/Pl complete
#pragma unroll
    for (int j = 0; j < 2; ++j) {        // Kt: 64 x 64
      int id = tid + 256 * j;
      *(bf16x8*)&Kt[(id >> 3) * 72 + (id & 7) * 8] = *(const bf16x8*)&Kg[((size_t)(m0 + (id >> 3))) * 64 + (id & 7) * 8];
    }
    for (int i = tid; i < 384; i += 256) // Vc: 48 x 64
      *(bf16x8*)&Vc[(i >> 3) * 72 + (i & 7) * 8] = *(const bf16x8*)&Vg[((size_t)(i >> 3)) * HW + m0 + (i & 7) * 8];
    __syncthreads();

    // S^T[m][n] = K·Q^T: wave owns m-strip 16wv, all 64 n (4 s-tiles)
    f32x4 sacc[4];
#pragma unroll
    for (int s = 0; s < 4; ++s) sacc[s] = (f32x4){0.f, 0.f, 0.f, 0.f};
#pragma unroll
    for (int ks = 0; ks < 2; ++ks) {
      bf16x8 af = *(const bf16x8*)&Kt[(16 * wv + l16) * 72 + 32 * ks + 8 * q4];
#pragma unroll
      for (int s = 0; s < 4; ++s)
        sacc[s] = __builtin_amdgcn_mfma_f32_16x16x32_bf16(af, qf[s][ks], sacc[s], 0, 0, 0);
    }

    // maxless softmax; C rows = m (16wv+4q4+r), col = n (16s+l16); packed b64 P writes
#pragma unroll
    for (int s = 0; s < 4; ++s) {
      float p0 = __expf(sacc[s][0]);
      float p1 = __expf(sacc[s][1]);
      float p2 = __expf(sacc[s][2]);
      float p3 = __expf(sacc[s][3]);
      lsub[s] += (p0 + p1) + (p2 + p3);
      bf16x4 pk = { (__bf16)p0, (__bf16)p1, (__bf16)p2, (__bf16)p3 };
      *(bf16x4*)&Pl[(16 * s + l16) * 72 + 16 * wv + 4 * q4] = pk;
    }
    __syncthreads();                     // Pl visible to all waves

    // O[n][c] += P·V^T: wave owns n-strip 16wv
#pragma unroll
    for (int ks = 0; ks < 2; ++ks) {
      bf16x8 pf = *(const bf16x8*)&Pl[(16 * wv + l16) * 72 + 32 * ks + 8 * q4];
#pragma unroll
      for (int ct = 0; ct < 3; ++ct) {
        bf16x8 vf = *(const bf16x8*)&Vc[(16 * ct + l16) * 72 + 32 * ks + 8 * q4];
        oacc[ct] = __builtin_amdgcn_mfma_f32_16x16x32_bf16(pf, vf, oacc[ct], 0, 0, 0);
      }
    }
  }

  // epilogue: lsub[s] holds partial l for n=16s+l16 summed over this wave's 4 m-rows (q4 group);
  // reduce over q4 groups (xor 16,32), then over waves via LDS (reuse Kt).
  __syncthreads();
  float* Lred = (float*)Kt;
#pragma unroll
  for (int s = 0; s < 4; ++s) {
    float v = lsub[s];
    v += __shfl_xor(v, 16, 64);
    v += __shfl_xor(v, 32, 64);
    if (q4 == 0) Lred[wv * 64 + 16 * s + l16] = v;
  }
  __syncthreads();
  size_t pbase = (size_t)bid * 3136;
  if (tid < 64)
    part[pbase + 3072 + tid] = Lred[tid] + Lred[64 + tid] + Lred[128 + tid] + Lred[192 + tid];
#pragma unroll
  for (int ct = 0; ct < 3; ++ct)
#pragma unroll
    for (int r = 0; r < 4; ++r) {
      int n = 16 * wv + 4 * q4 + r;
      part[pbase + (size_t)n * 48 + 16 * ct + l16] = oacc[ct][r];
    }
}

// ---------------- merge 4 chunks + normalize -> Xt_att bf16 [(b*4096+n)][192] ----------------
// grid 512 = bh*64 + nt
__global__ __launch_bounds__(256) void attn_merge_kernel(const float* __restrict__ part, __bf16* __restrict__ Xt) {
  const int bid = blockIdx.x;
  const int bh = bid >> 6, nt = bid & 63;
  const int b = bh >> 2, h = bh & 3;
  const int n0 = nt * 64;
  const int t = threadIdx.x;
  __shared__ float linv[64];
  if (t < 64) {
    float s = 0.f;
#pragma unroll
    for (int ch = 0; ch < 4; ++ch) s += part[((size_t)(ch * 512 + bid)) * 3136 + 3072 + t];
    linv[t] = 1.f / s;
  }
  __syncthreads();
#pragma unroll
  for (int j = 0; j < 3; ++j) {
    int id = t + 256 * j;          // 768 f32x4 chunks: n = id/12, c4 = (id%12)*4
    int n = id / 12, cc = (id - n * 12) * 4;
    f32x4 s = (f32x4){0.f, 0.f, 0.f, 0.f};
#pragma unroll
    for (int ch = 0; ch < 4; ++ch) s += *(const f32x4*)&part[((size_t)(ch * 512 + bid)) * 3136 + (size_t)n * 48 + cc];
    float li = linv[n];
    bf16x4 ov = { (__bf16)(s.x * li), (__bf16)(s.y * li), (__bf16)(s.z * li), (__bf16)(s.w * li) };
    *(bf16x4*)&Xt[((size_t)((b << 12) + n0 + n)) * DIMC + h * DH + cc] = ov;
  }
}

extern "C" void kernel_launch(void* const* d_in, const int* in_sizes, int n_in,
                              void* d_out, int out_size, void* d_ws, size_t ws_size,
                              hipStream_t stream) {
  const float* x        = (const float*)d_in[0];
  const float* ln1_w    = (const float*)d_in[1];
  const float* ln1_b    = (const float*)d_in[2];
  const float* qkv_w    = (const float*)d_in[3];
  const float* qkv_b    = (const float*)d_in[4];
  const float* qkv_dw_w = (const float*)d_in[5];
  const float* qkv_dw_b = (const float*)d_in[6];
  const float* temperature = (const float*)d_in[7];
  const float* proj_w   = (const float*)d_in[8];
  const float* proj_b   = (const float*)d_in[9];
  const float* ln2_w    = (const float*)d_in[10];
  const float* ln2_b    = (const float*)d_in[11];
  const float* pin_w    = (const float*)d_in[12];
  const float* pin_b    = (const float*)d_in[13];
  const float* gdfn_dw_w = (const float*)d_in[14];
  const float* gdfn_dw_b = (const float*)d_in[15];
  const float* pout_w   = (const float*)d_in[16];
  const float* pout_b   = (const float*)d_in[17];
  float* out = (float*)d_out;
  float* ws = (float*)d_ws;

  // ---- workspace layout (float offsets) ----
  __bf16* wb_qkv  = (__bf16*)(ws + 0);          // 55296 f
  __bf16* wb_proj = (__bf16*)(ws + 55296);      // 18432 f
  __bf16* wb_pin  = (__bf16*)(ws + 73728);      // 97920 f
  __bf16* wb_pout = (__bf16*)(ws + 171648);     // 49152 f
  float* sc1 = ws + 220800;
  float* sh1 = ws + 221184;
  float* sc2 = ws + 221568;
  float* sh2 = ws + 221952;                     // ends 222336
  // region B @222336: Xt1/Xt2 overlap Qbf; Q/K/V bf16
  __bf16* Xt1 = (__bf16*)(ws + 222336);
  __bf16* Xt2 = (__bf16*)(ws + 222336);
  __bf16* Qbf = (__bf16*)(ws + 222336);         // 1,048,576 f
  __bf16* Kbf = (__bf16*)(ws + 1270912);        // 1,048,576 f
  __bf16* Vbf = (__bf16*)(ws + 2319488);        // 786,432 f -> ends 3,105,920
  // region C @3,105,920: qkvb bf16 -> later Xt_att -> later hid
  __bf16* qkvb   = (__bf16*)(ws + 3105920);
  __bf16* Xt_att = (__bf16*)(ws + 3105920);
  __bf16* hid    = (__bf16*)(ws + 3105920);     // ends 7,283,840
  // region D @5,465,216: qdwb (dead before attn) then Opart
  __bf16* qdwb  = (__bf16*)(ws + 5465216);
  float*  Opart = ws + 5465216;                 // 2048*3136 = 6,422,528 f -> ends 11,887,744
  __bf16* gate  = (__bf16*)(ws + 7283840);      // 2,088,960 f (phase B, Opart dead)
  // total 11,887,744 f = 47.6 MB

  wcvt4_kernel<<<1725, 256, 0, stream>>>(qkv_w, proj_w, pin_w, pout_w, wb_qkv, wb_proj, wb_pin, wb_pout);

  // ---- phase A ----
  ln_stats_kernel<<<2 * DIMC, 256, 0, stream>>>(x, ln1_w, ln1_b, sc1, sh1);
  ln_apply_t_kernel<<<dim3(64, 6, 2), 256, 0, stream>>>(x, sc1, sh1, Xt1);
  gemm_kernel<<<dim3(64, 9), 256, 0, stream>>>(wb_qkv, Xt1, qkv_b, nullptr, nullptr, qkvb, 576, 192, 1);
  dwconv_split_kernel<<<1152, 256, 0, stream>>>(qkvb, qkv_dw_w, qkv_dw_b, qdwb, Vbf);
  prep_qk_kernel<<<128, 256, 0, stream>>>(qdwb, temperature, Qbf, Kbf);
  attn_split_kernel<<<2048, 256, 0, stream>>>(Qbf, Kbf, Vbf, Opart);
  attn_merge_kernel<<<512, 256, 0, stream>>>(Opart, Xt_att);
  gemm_kernel<<<dim3(64, 3), 256, 0, stream>>>(wb_proj, Xt_att, proj_b, x, out, nullptr, 192, 192, 2);

  // ---- phase B ----
  ln_stats_kernel<<<2 * DIMC, 256, 0, stream>>>(out, ln2_w, ln2_b, sc2, sh2);
  ln_apply_t_kernel<<<dim3(64, 6, 2), 256, 0, stream>>>(out, sc2, sh2, Xt2);
  gemm_kernel<<<dim3(64, 16), 256, 0, stream>>>(wb_pin, Xt2, pin_b, nullptr, nullptr, hid, 1020, 192, 1);
  gdfn_dw_gate_kernel<<<2 * HIDC, 256, 0, stream>>>(hid, gdfn_dw_w, gdfn_dw_b, gate);
  gemm_kernel<<<dim3(64, 3), 256, 0, stream>>>(wb_pout, (const __bf16*)gate, pout_b, out, out, nullptr, 192, 512, 3);
}